// Round 1
// baseline (6415.146 us; speedup 1.0000x reference)
//
#include <hip/hip_runtime.h>
#include <cstdint>
#include <cmath>

#define NNODES 100000
#define NEDGES 1600000

// ---------------- init aggr to -inf ----------------
__global__ __launch_bounds__(256) void init_neginf_kernel(float4* __restrict__ p, int n4) {
    int i = blockIdx.x * 256 + threadIdx.x;
    if (i < n4) {
        float v = __uint_as_float(0xFF800000u);  // -inf
        p[i] = make_float4(v, v, v, v);
    }
}

// ---------------- scatter-max: aggr[dst] = max(x[src]) ----------------
// 32 threads per edge, each thread owns 4 channels (float4 gather).
// Signed-int atomicMax for val>=0, unsigned atomicMin for val<0:
// monotone-correct under mixed signs with -inf init. (-0.0 edge case is
// measure-zero for random normal inputs.)
__global__ __launch_bounds__(256) void scatter_max_kernel(
        const float* __restrict__ x,
        const int* __restrict__ src,
        const int* __restrict__ dst,
        float* __restrict__ aggr,
        int nE) {
    int t = blockIdx.x * 256 + threadIdx.x;
    int e = t >> 5;
    if (e >= nE) return;
    int lane = t & 31;
    int s = src[e];
    int d = dst[e];
    float4 v = *(const float4*)(x + (size_t)s * 128 + lane * 4);
    float* out = aggr + (size_t)d * 128 + lane * 4;
    float vals[4] = {v.x, v.y, v.z, v.w};
#pragma unroll
    for (int j = 0; j < 4; ++j) {
        float val = vals[j];
        if (val >= 0.0f) atomicMax((int*)(out + j), __float_as_int(val));
        else             atomicMin((unsigned int*)(out + j), __float_as_uint(val));
    }
}

// ---------------- fused SAGE GEMM ----------------
// C[M,BN] = act( fix(Aagg) @ Wl + bias + Aroot @ Wr )
// Treated as one GEMM with K=256: A' = [fix(Aagg) | Aroot], B' = [Wl ; Wr].
// BM=64, BK=32 → K-chunks 0..3 from Aagg/Wl, 4..7 from Aroot/Wr (no per-elem branch).
template<int BN, bool RELU>
__global__ __launch_bounds__(256) void sage_gemm_kernel(
        const float* __restrict__ Aagg,   // [M,128]  (-inf -> 0 fixup on load)
        const float* __restrict__ Aroot,  // [M,128]
        const float* __restrict__ Wl,     // [128,BN] row-major
        const float* __restrict__ Wr,     // [128,BN]
        const float* __restrict__ bias,   // [BN]
        float* __restrict__ C,            // [M,BN]
        int M) {
    constexpr int BM = 64, BK = 32;
    constexpr int TN = BN / 16;  // 8 (BN=128) or 4 (BN=64)
    constexpr int TM = 4;
    __shared__ float As[BM][BK + 1];
    __shared__ float Bs[BK][BN];

    const int tid = threadIdx.x;
    const int col_t = tid & 15;   // 16 thread-cols * TN
    const int row_t = tid >> 4;   // 16 thread-rows * TM
    const int rowBase = blockIdx.x * BM;

    float acc[TM][TN];
#pragma unroll
    for (int j = 0; j < TM; ++j)
#pragma unroll
        for (int i = 0; i < TN; ++i) acc[j][i] = 0.0f;

    for (int kt = 0; kt < 8; ++kt) {
        const bool isAgg = (kt < 4);
        const float* Asrc = isAgg ? Aagg : Aroot;
        const float* Bsrc = isAgg ? Wl : Wr;
        const int kofs = (isAgg ? kt : kt - 4) * BK;

        // A tile: 64 rows x 32 cols = 512 float4, 2 per thread
#pragma unroll
        for (int it = 0; it < 2; ++it) {
            int i = tid + it * 256;
            int r = i >> 3;
            int c4 = (i & 7) * 4;
            int grow = rowBase + r;
            float4 v = make_float4(0.f, 0.f, 0.f, 0.f);
            if (grow < M)
                v = *(const float4*)(Asrc + (size_t)grow * 128 + kofs + c4);
            if (isAgg) {
                if (__float_as_uint(v.x) == 0xFF800000u) v.x = 0.0f;
                if (__float_as_uint(v.y) == 0xFF800000u) v.y = 0.0f;
                if (__float_as_uint(v.z) == 0xFF800000u) v.z = 0.0f;
                if (__float_as_uint(v.w) == 0xFF800000u) v.w = 0.0f;
            }
            As[r][c4 + 0] = v.x;
            As[r][c4 + 1] = v.y;
            As[r][c4 + 2] = v.z;
            As[r][c4 + 3] = v.w;
        }
        // B tile: 32 x BN floats = 8*BN float4
#pragma unroll
        for (int it = 0; it < (8 * BN) / 256; ++it) {
            int i = tid + it * 256;
            int k = i / (BN / 4);
            int c4 = (i % (BN / 4)) * 4;
            float4 v = *(const float4*)(Bsrc + (size_t)(kofs + k) * BN + c4);
            *(float4*)&Bs[k][c4] = v;
        }
        __syncthreads();

#pragma unroll
        for (int k = 0; k < BK; ++k) {
            float a[TM], b[TN];
#pragma unroll
            for (int j = 0; j < TM; ++j) a[j] = As[row_t * TM + j][k];
#pragma unroll
            for (int i = 0; i < TN; ++i) b[i] = Bs[k][col_t * TN + i];
#pragma unroll
            for (int j = 0; j < TM; ++j)
#pragma unroll
                for (int i = 0; i < TN; ++i)
                    acc[j][i] = fmaf(a[j], b[i], acc[j][i]);
        }
        __syncthreads();
    }

#pragma unroll
    for (int j = 0; j < TM; ++j) {
        int grow = rowBase + row_t * TM + j;
        if (grow >= M) continue;
#pragma unroll
        for (int i = 0; i < TN; ++i) {
            int col = col_t * TN + i;
            float v = acc[j][i] + bias[col];
            if (RELU) v = fmaxf(v, 0.0f);
            C[(size_t)grow * BN + col] = v;
        }
    }
}

extern "C" void kernel_launch(void* const* d_in, const int* in_sizes, int n_in,
                              void* d_out, int out_size, void* d_ws, size_t ws_size,
                              hipStream_t stream) {
    const float* x   = (const float*)d_in[0];
    const int*   ei  = (const int*)d_in[1];   // [2, E] int
    const float* W1l = (const float*)d_in[2];
    const float* b1l = (const float*)d_in[3];
    const float* W1r = (const float*)d_in[4];
    const float* W2l = (const float*)d_in[5];
    const float* b2l = (const float*)d_in[6];
    const float* W2r = (const float*)d_in[7];
    float* out = (float*)d_out;

    const int* src = ei;
    const int* dst = ei + NEDGES;

    float* aggr = (float*)d_ws;                    // 100000*128 floats = 51.2 MB
    float* h    = aggr + (size_t)NNODES * 128;     // 100000*128 floats = 51.2 MB

    const int n4 = NNODES * 128 / 4;
    const int initGrid = (n4 + 255) / 256;
    const int scatGrid = (int)(((long long)NEDGES * 32 + 255) / 256);  // 200000
    const int gemmGrid = (NNODES + 63) / 64;

    // Layer 1
    init_neginf_kernel<<<initGrid, 256, 0, stream>>>((float4*)aggr, n4);
    scatter_max_kernel<<<scatGrid, 256, 0, stream>>>(x, src, dst, aggr, NEDGES);
    sage_gemm_kernel<128, true><<<gemmGrid, 256, 0, stream>>>(aggr, x, W1l, W1r, b1l, h, NNODES);
    // Layer 2
    init_neginf_kernel<<<initGrid, 256, 0, stream>>>((float4*)aggr, n4);
    scatter_max_kernel<<<scatGrid, 256, 0, stream>>>(h, src, dst, aggr, NEDGES);
    sage_gemm_kernel<64, false><<<gemmGrid, 256, 0, stream>>>(aggr, h, W2l, W2r, b2l, out, NNODES);
}

// Round 2
// 702.184 us; speedup vs baseline: 9.1360x; 9.1360x over previous
//
#include <hip/hip_runtime.h>
#include <cstdint>
#include <cmath>

#define NNODES 100000
#define NEDGES 1600000
#define NB_SCAN ((NNODES + 255) / 256)   // 391 blocks for the scan

// ---------------- zero two count arrays ----------------
__global__ __launch_bounds__(256) void zero_kernel(int* __restrict__ p, int n) {
    int i = blockIdx.x * 256 + threadIdx.x;
    if (i < n) p[i] = 0;
}

// ---------------- histogram of dst ----------------
__global__ __launch_bounds__(256) void hist_kernel(const int* __restrict__ dst,
                                                   int* __restrict__ cnt, int nE) {
    int e = blockIdx.x * 256 + threadIdx.x;
    if (e < nE) atomicAdd(&cnt[dst[e]], 1);
}

// ---------------- scan step 1: per-block sums ----------------
__global__ __launch_bounds__(256) void scan1_kernel(const int* __restrict__ cnt,
                                                    int* __restrict__ partial, int n) {
    __shared__ int s[256];
    int t = threadIdx.x;
    int i = blockIdx.x * 256 + t;
    s[t] = (i < n) ? cnt[i] : 0;
    __syncthreads();
    for (int off = 128; off > 0; off >>= 1) {
        if (t < off) s[t] += s[t + off];
        __syncthreads();
    }
    if (t == 0) partial[blockIdx.x] = s[0];
}

// ---------------- scan step 2: serial scan of block sums (tiny) ----------------
__global__ void scan2_kernel(int* __restrict__ partial, int nb, int* __restrict__ rowptr) {
    if (threadIdx.x == 0 && blockIdx.x == 0) {
        int total = 0;
        for (int b = 0; b < nb; ++b) {
            int v = partial[b];
            partial[b] = total;
            total += v;
        }
        rowptr[NNODES] = total;   // == NEDGES
    }
}

// ---------------- scan step 3: in-block exclusive scan + offset ----------------
__global__ __launch_bounds__(256) void scan3_kernel(const int* __restrict__ cnt,
                                                    const int* __restrict__ partial,
                                                    int* __restrict__ rowptr, int n) {
    __shared__ int s[256];
    int t = threadIdx.x;
    int i = blockIdx.x * 256 + t;
    int val = (i < n) ? cnt[i] : 0;
    s[t] = val;
    __syncthreads();
    for (int off = 1; off < 256; off <<= 1) {
        int add = (t >= off) ? s[t - off] : 0;
        __syncthreads();
        s[t] += add;
        __syncthreads();
    }
    if (i < n) rowptr[i] = partial[blockIdx.x] + s[t] - val;  // exclusive
}

// ---------------- scatter edges into dst-sorted order ----------------
__global__ __launch_bounds__(256) void scatter_edges_kernel(
        const int* __restrict__ src, const int* __restrict__ dst,
        const int* __restrict__ rowptr, int* __restrict__ fill,
        int* __restrict__ sortedSrc, int nE) {
    int e = blockIdx.x * 256 + threadIdx.x;
    if (e >= nE) return;
    int d = dst[e];
    int pos = rowptr[d] + atomicAdd(&fill[d], 1);
    sortedSrc[pos] = src[e];
}

// ---------------- aggregation: one wave per node, register max ----------------
// lane owns 2 channels (float2); per edge one coalesced 512B row gather.
__global__ __launch_bounds__(256) void aggregate_max_kernel(
        const float* __restrict__ x,
        const int* __restrict__ rowptr,
        const int* __restrict__ sortedSrc,
        float* __restrict__ aggr, int nN) {
    int wave = threadIdx.x >> 6;
    int lane = threadIdx.x & 63;
    int n = blockIdx.x * 4 + wave;
    if (n >= nN) return;
    int beg = rowptr[n];
    int end = rowptr[n + 1];
    float2 acc = make_float2(-INFINITY, -INFINITY);
    const float2* xv = (const float2*)x;
    for (int base = beg; base < end; base += 64) {
        int myid = (base + lane < end) ? sortedSrc[base + lane] : 0;
        int m = end - base; if (m > 64) m = 64;
        for (int j = 0; j < m; ++j) {
            int s = __shfl(myid, j);
            float2 v = xv[(size_t)s * 64 + lane];
            acc.x = fmaxf(acc.x, v.x);
            acc.y = fmaxf(acc.y, v.y);
        }
    }
    float2 outv = (end > beg) ? acc : make_float2(0.0f, 0.0f);  // isolated -> 0
    ((float2*)aggr)[(size_t)n * 64 + lane] = outv;
}

// ---------------- fused SAGE GEMM ----------------
// C[M,BN] = act( Aagg @ Wl + bias + Aroot @ Wr ), one GEMM with K=256.
template<int BN, bool RELU>
__global__ __launch_bounds__(256) void sage_gemm_kernel(
        const float* __restrict__ Aagg,   // [M,128]
        const float* __restrict__ Aroot,  // [M,128]
        const float* __restrict__ Wl,     // [128,BN] row-major
        const float* __restrict__ Wr,     // [128,BN]
        const float* __restrict__ bias,   // [BN]
        float* __restrict__ C,            // [M,BN]
        int M) {
    constexpr int BM = 64, BK = 32;
    constexpr int TN = BN / 16;  // 8 (BN=128) or 4 (BN=64)
    constexpr int TM = 4;
    __shared__ float As[BM][BK + 1];
    __shared__ float Bs[BK][BN];

    const int tid = threadIdx.x;
    const int col_t = tid & 15;
    const int row_t = tid >> 4;
    const int rowBase = blockIdx.x * BM;

    float acc[TM][TN];
#pragma unroll
    for (int j = 0; j < TM; ++j)
#pragma unroll
        for (int i = 0; i < TN; ++i) acc[j][i] = 0.0f;

    for (int kt = 0; kt < 8; ++kt) {
        const bool isAgg = (kt < 4);
        const float* Asrc = isAgg ? Aagg : Aroot;
        const float* Bsrc = isAgg ? Wl : Wr;
        const int kofs = (isAgg ? kt : kt - 4) * BK;

#pragma unroll
        for (int it = 0; it < 2; ++it) {
            int i = tid + it * 256;
            int r = i >> 3;
            int c4 = (i & 7) * 4;
            int grow = rowBase + r;
            float4 v = make_float4(0.f, 0.f, 0.f, 0.f);
            if (grow < M)
                v = *(const float4*)(Asrc + (size_t)grow * 128 + kofs + c4);
            As[r][c4 + 0] = v.x;
            As[r][c4 + 1] = v.y;
            As[r][c4 + 2] = v.z;
            As[r][c4 + 3] = v.w;
        }
#pragma unroll
        for (int it = 0; it < (8 * BN) / 256; ++it) {
            int i = tid + it * 256;
            int k = i / (BN / 4);
            int c4 = (i % (BN / 4)) * 4;
            float4 v = *(const float4*)(Bsrc + (size_t)(kofs + k) * BN + c4);
            *(float4*)&Bs[k][c4] = v;
        }
        __syncthreads();

#pragma unroll
        for (int k = 0; k < BK; ++k) {
            float a[TM], b[TN];
#pragma unroll
            for (int j = 0; j < TM; ++j) a[j] = As[row_t * TM + j][k];
#pragma unroll
            for (int i = 0; i < TN; ++i) b[i] = Bs[k][col_t * TN + i];
#pragma unroll
            for (int j = 0; j < TM; ++j)
#pragma unroll
                for (int i = 0; i < TN; ++i)
                    acc[j][i] = fmaf(a[j], b[i], acc[j][i]);
        }
        __syncthreads();
    }

#pragma unroll
    for (int j = 0; j < TM; ++j) {
        int grow = rowBase + row_t * TM + j;
        if (grow >= M) continue;
#pragma unroll
        for (int i = 0; i < TN; ++i) {
            int col = col_t * TN + i;
            float v = acc[j][i] + bias[col];
            if (RELU) v = fmaxf(v, 0.0f);
            C[(size_t)grow * BN + col] = v;
        }
    }
}

extern "C" void kernel_launch(void* const* d_in, const int* in_sizes, int n_in,
                              void* d_out, int out_size, void* d_ws, size_t ws_size,
                              hipStream_t stream) {
    const float* x   = (const float*)d_in[0];
    const int*   ei  = (const int*)d_in[1];   // [2, E]
    const float* W1l = (const float*)d_in[2];
    const float* b1l = (const float*)d_in[3];
    const float* W1r = (const float*)d_in[4];
    const float* W2l = (const float*)d_in[5];
    const float* b2l = (const float*)d_in[6];
    const float* W2r = (const float*)d_in[7];
    float* out = (float*)d_out;

    const int* src = ei;
    const int* dst = ei + NEDGES;

    // ---- workspace layout ----
    char* ws = (char*)d_ws;
    float* aggr      = (float*)ws;                                ws += (size_t)NNODES * 128 * 4;  // 51.2 MB
    float* h         = (float*)ws;                                ws += (size_t)NNODES * 128 * 4;  // 51.2 MB
    int*   sortedSrc = (int*)ws;                                  ws += (size_t)NEDGES * 4;        // 6.4 MB
    int*   rowptr    = (int*)ws;                                  ws += (size_t)(NNODES + 1) * 4;
    int*   cnt       = (int*)ws;                                  ws += (size_t)NNODES * 4;
    int*   fill      = (int*)ws;                                  ws += (size_t)NNODES * 4;
    int*   partial   = (int*)ws;                                  ws += (size_t)NB_SCAN * 4;

    const int gE = (NEDGES + 255) / 256;
    const int gN = NB_SCAN;
    const int gAgg = (NNODES + 3) / 4;
    const int gGemm = (NNODES + 63) / 64;

    // ---- build dst-sorted CSR (once, reused by both layers) ----
    zero_kernel<<<(2 * NNODES + 255) / 256, 256, 0, stream>>>(cnt, 2 * NNODES);  // cnt + fill adjacent
    hist_kernel<<<gE, 256, 0, stream>>>(dst, cnt, NEDGES);
    scan1_kernel<<<gN, 256, 0, stream>>>(cnt, partial, NNODES);
    scan2_kernel<<<1, 64, 0, stream>>>(partial, NB_SCAN, rowptr);
    scan3_kernel<<<gN, 256, 0, stream>>>(cnt, partial, rowptr, NNODES);
    scatter_edges_kernel<<<gE, 256, 0, stream>>>(src, dst, rowptr, fill, sortedSrc, NEDGES);

    // ---- layer 1 ----
    aggregate_max_kernel<<<gAgg, 256, 0, stream>>>(x, rowptr, sortedSrc, aggr, NNODES);
    sage_gemm_kernel<128, true><<<gGemm, 256, 0, stream>>>(aggr, x, W1l, W1r, b1l, h, NNODES);
    // ---- layer 2 ----
    aggregate_max_kernel<<<gAgg, 256, 0, stream>>>(h, rowptr, sortedSrc, aggr, NNODES);
    sage_gemm_kernel<64, false><<<gGemm, 256, 0, stream>>>(aggr, h, W2l, W2r, b2l, out, NNODES);
}

// Round 3
// 564.459 us; speedup vs baseline: 11.3651x; 1.2440x over previous
//
#include <hip/hip_runtime.h>
#include <cstdint>
#include <cmath>

#define NNODES 100000
#define NEDGES 1600000
#define NB_SCAN ((NNODES + 255) / 256)

typedef __attribute__((ext_vector_type(8))) __bf16 bf16x8;
typedef __attribute__((ext_vector_type(4))) float f32x4;

__device__ __forceinline__ unsigned short f2bf_rne(float f) {
    unsigned int u = __float_as_uint(f);
    u += 0x7fffu + ((u >> 16) & 1u);
    return (unsigned short)(u >> 16);
}

// ---------------- zero ----------------
__global__ __launch_bounds__(256) void zero_kernel(int* __restrict__ p, int n) {
    int i = blockIdx.x * 256 + threadIdx.x;
    if (i < n) p[i] = 0;
}

// ---------------- convert fp32 -> packed bf16 ----------------
__global__ __launch_bounds__(256) void convert_bf16_kernel(const float4* __restrict__ in,
                                                           uint2* __restrict__ out, int n4) {
    int i = blockIdx.x * 256 + threadIdx.x;
    if (i >= n4) return;
    float4 v = in[i];
    uint2 o;
    o.x = (unsigned)f2bf_rne(v.x) | ((unsigned)f2bf_rne(v.y) << 16);
    o.y = (unsigned)f2bf_rne(v.z) | ((unsigned)f2bf_rne(v.w) << 16);
    out[i] = o;
}

// ---------------- histogram of dst ----------------
__global__ __launch_bounds__(256) void hist_kernel(const int* __restrict__ dst,
                                                   int* __restrict__ cnt, int nE) {
    int e = blockIdx.x * 256 + threadIdx.x;
    if (e < nE) atomicAdd(&cnt[dst[e]], 1);
}

// ---------------- scan ----------------
__global__ __launch_bounds__(256) void scan1_kernel(const int* __restrict__ cnt,
                                                    int* __restrict__ partial, int n) {
    __shared__ int s[256];
    int t = threadIdx.x;
    int i = blockIdx.x * 256 + t;
    s[t] = (i < n) ? cnt[i] : 0;
    __syncthreads();
    for (int off = 128; off > 0; off >>= 1) {
        if (t < off) s[t] += s[t + off];
        __syncthreads();
    }
    if (t == 0) partial[blockIdx.x] = s[0];
}

__global__ void scan2_kernel(int* __restrict__ partial, int nb, int* __restrict__ rowptr) {
    if (threadIdx.x == 0 && blockIdx.x == 0) {
        int total = 0;
        for (int b = 0; b < nb; ++b) {
            int v = partial[b];
            partial[b] = total;
            total += v;
        }
        rowptr[NNODES] = total;
    }
}

__global__ __launch_bounds__(256) void scan3_kernel(const int* __restrict__ cnt,
                                                    const int* __restrict__ partial,
                                                    int* __restrict__ rowptr, int n) {
    __shared__ int s[256];
    int t = threadIdx.x;
    int i = blockIdx.x * 256 + t;
    int val = (i < n) ? cnt[i] : 0;
    s[t] = val;
    __syncthreads();
    for (int off = 1; off < 256; off <<= 1) {
        int add = (t >= off) ? s[t - off] : 0;
        __syncthreads();
        s[t] += add;
        __syncthreads();
    }
    if (i < n) rowptr[i] = partial[blockIdx.x] + s[t] - val;
}

// ---------------- scatter edges into dst-sorted order ----------------
__global__ __launch_bounds__(256) void scatter_edges_kernel(
        const int* __restrict__ src, const int* __restrict__ dst,
        const int* __restrict__ rowptr, int* __restrict__ fill,
        int* __restrict__ sortedSrc, int nE) {
    int e = blockIdx.x * 256 + threadIdx.x;
    if (e >= nE) return;
    int d = dst[e];
    int pos = rowptr[d] + atomicAdd(&fill[d], 1);
    sortedSrc[pos] = src[e];
}

// ---------------- aggregation (bf16 rows): one wave per node ----------------
// lane owns 2 channels (one packed uint = 2 bf16); per edge one 256B row gather.
__global__ __launch_bounds__(256) void aggregate_max_bf16(
        const unsigned int* __restrict__ xb,   // [M][64] packed bf16x2
        const int* __restrict__ rowptr,
        const int* __restrict__ sortedSrc,
        unsigned int* __restrict__ aggrb,      // [M][64] packed bf16x2
        int nN) {
    int wave = threadIdx.x >> 6;
    int lane = threadIdx.x & 63;
    int n = blockIdx.x * 4 + wave;
    if (n >= nN) return;
    int beg = rowptr[n];
    int end = rowptr[n + 1];
    float m0 = -INFINITY, m1 = -INFINITY;
    for (int base = beg; base < end; base += 64) {
        int myid = (base + lane < end) ? sortedSrc[base + lane] : 0;
        int m = end - base; if (m > 64) m = 64;
        for (int j = 0; j < m; ++j) {
            int s = __shfl(myid, j);
            unsigned int p = xb[(size_t)s * 64 + lane];
            float f0 = __uint_as_float(p << 16);
            float f1 = __uint_as_float(p & 0xffff0000u);
            m0 = fmaxf(m0, f0);
            m1 = fmaxf(m1, f1);
        }
    }
    unsigned int outv;
    if (end > beg)  // values are exactly bf16 -> truncation is exact
        outv = (__float_as_uint(m1) & 0xffff0000u) | (__float_as_uint(m0) >> 16);
    else
        outv = 0u;   // isolated node -> 0
    aggrb[(size_t)n * 64 + lane] = outv;
}

// ---------------- MFMA bf16 fused SAGE GEMM ----------------
// C[M,BN] = act( Aagg @ Wl + bias + Aroot @ Wr ), K=256 in two 128-halves.
// Bs stored transposed [n][k], stride 136 elems (272B = 68 dwords === 4 mod 32
// -> b128 reads hit uniform 8 accesses/bank = conflict-free baseline).
template<int BN, bool RELU, typename OutT>
__global__ __launch_bounds__(256) void sage_gemm_mfma(
        const unsigned short* __restrict__ Aagg,   // [M][128] bf16
        const unsigned short* __restrict__ Aroot,  // [M][128] bf16
        const float* __restrict__ Wl,              // [128][BN] f32
        const float* __restrict__ Wr,              // [128][BN] f32
        const float* __restrict__ bias,            // [BN] f32
        OutT* __restrict__ C,                      // [M][BN]
        int M) {
    constexpr int KP = 136;
    constexpr int NT = BN / 16;
    __shared__ __align__(16) unsigned short Bs[BN * KP];

    const int tid = threadIdx.x;
    const int wave = tid >> 6;
    const int lane = tid & 63;
    const int quad = lane >> 4;
    const int mrow = lane & 15;

    const int rowA = blockIdx.x * 64 + wave * 16 + mrow;       // A-fragment row
    const int rowAc = (rowA < M) ? rowA : 0;                   // clamp OOB loads
    const int rowD = blockIdx.x * 64 + wave * 16 + quad * 4;   // D row base (+reg)

    f32x4 acc[NT];
#pragma unroll
    for (int nt = 0; nt < NT; ++nt) acc[nt] = (f32x4){0.f, 0.f, 0.f, 0.f};

    for (int half = 0; half < 2; ++half) {
        const float* W = half ? Wr : Wl;
        const unsigned short* Asrc = half ? Aroot : Aagg;
        __syncthreads();  // protect Bs reuse across halves
        for (int i = tid; i < BN * 128; i += 256) {
            int n = i % BN;       // consecutive tid -> consecutive n: coalesced W row read
            int k = i / BN;
            Bs[n * KP + k] = f2bf_rne(W[k * BN + n]);
        }
        __syncthreads();
#pragma unroll
        for (int kt = 0; kt < 4; ++kt) {
            bf16x8 a = *(const bf16x8*)(Asrc + (size_t)rowAc * 128 + kt * 32 + quad * 8);
#pragma unroll
            for (int nt = 0; nt < NT; ++nt) {
                bf16x8 b = *(const bf16x8*)(&Bs[(nt * 16 + mrow) * KP + kt * 32 + quad * 8]);
                acc[nt] = __builtin_amdgcn_mfma_f32_16x16x32_bf16(a, b, acc[nt], 0, 0, 0);
            }
        }
    }

    // epilogue: D layout col=lane&15, row=quad*4+reg
#pragma unroll
    for (int nt = 0; nt < NT; ++nt) {
        int col = nt * 16 + mrow;
        float bv = bias[col];
#pragma unroll
        for (int r = 0; r < 4; ++r) {
            int grow = rowD + r;
            if (grow < M) {
                float v = acc[nt][r] + bv;
                if (RELU) v = fmaxf(v, 0.0f);
                if constexpr (sizeof(OutT) == 2)
                    C[(size_t)grow * BN + col] = (OutT)f2bf_rne(v);
                else
                    C[(size_t)grow * BN + col] = (OutT)v;
            }
        }
    }
}

extern "C" void kernel_launch(void* const* d_in, const int* in_sizes, int n_in,
                              void* d_out, int out_size, void* d_ws, size_t ws_size,
                              hipStream_t stream) {
    const float* x   = (const float*)d_in[0];
    const int*   ei  = (const int*)d_in[1];
    const float* W1l = (const float*)d_in[2];
    const float* b1l = (const float*)d_in[3];
    const float* W1r = (const float*)d_in[4];
    const float* W2l = (const float*)d_in[5];
    const float* b2l = (const float*)d_in[6];
    const float* W2r = (const float*)d_in[7];
    float* out = (float*)d_out;

    const int* src = ei;
    const int* dst = ei + NEDGES;

    // ---- workspace layout (all bf16 feature buffers) ----
    char* ws = (char*)d_ws;
    unsigned short* xb    = (unsigned short*)ws; ws += (size_t)NNODES * 128 * 2;  // 25.6 MB
    unsigned short* hb    = (unsigned short*)ws; ws += (size_t)NNODES * 128 * 2;  // 25.6 MB
    unsigned short* aggrb = (unsigned short*)ws; ws += (size_t)NNODES * 128 * 2;  // 25.6 MB
    int* sortedSrc = (int*)ws;  ws += (size_t)NEDGES * 4;                         // 6.4 MB
    int* rowptr    = (int*)ws;  ws += (size_t)(NNODES + 1) * 4;
    int* cnt       = (int*)ws;  ws += (size_t)NNODES * 4;
    int* fill      = (int*)ws;  ws += (size_t)NNODES * 4;
    int* partial   = (int*)ws;  ws += (size_t)NB_SCAN * 4;

    const int gE = (NEDGES + 255) / 256;
    const int gN = NB_SCAN;
    const int gAgg = (NNODES + 3) / 4;
    const int gGemm = (NNODES + 63) / 64;
    const int n4 = NNODES * 128 / 4;  // 3.2M float4 groups

    // ---- build dst-sorted CSR + bf16 copy of x (independent streams of work) ----
    zero_kernel<<<(2 * NNODES + 255) / 256, 256, 0, stream>>>(cnt, 2 * NNODES);
    convert_bf16_kernel<<<(n4 + 255) / 256, 256, 0, stream>>>((const float4*)x, (uint2*)xb, n4);
    hist_kernel<<<gE, 256, 0, stream>>>(dst, cnt, NEDGES);
    scan1_kernel<<<gN, 256, 0, stream>>>(cnt, partial, NNODES);
    scan2_kernel<<<1, 64, 0, stream>>>(partial, NB_SCAN, rowptr);
    scan3_kernel<<<gN, 256, 0, stream>>>(cnt, partial, rowptr, NNODES);
    scatter_edges_kernel<<<gE, 256, 0, stream>>>(src, dst, rowptr, fill, sortedSrc, NEDGES);

    // ---- layer 1 ----
    aggregate_max_bf16<<<gAgg, 256, 0, stream>>>((const unsigned int*)xb, rowptr, sortedSrc,
                                                 (unsigned int*)aggrb, NNODES);
    sage_gemm_mfma<128, true, unsigned short><<<gGemm, 256, 0, stream>>>(
        aggrb, xb, W1l, W1r, b1l, hb, NNODES);
    // ---- layer 2 ----
    aggregate_max_bf16<<<gAgg, 256, 0, stream>>>((const unsigned int*)hb, rowptr, sortedSrc,
                                                 (unsigned int*)aggrb, NNODES);
    sage_gemm_mfma<64, false, float><<<gGemm, 256, 0, stream>>>(
        aggrb, hb, W2l, W2r, b2l, out, NNODES);
}

// Round 4
// 442.215 us; speedup vs baseline: 14.5068x; 1.2764x over previous
//
#include <hip/hip_runtime.h>
#include <cstdint>
#include <cmath>

#define NNODES 100000
#define NEDGES 1600000
#define NB_SCAN ((NNODES + 255) / 256)   // 391 <= 512

typedef __attribute__((ext_vector_type(8))) __bf16 bf16x8;
typedef __attribute__((ext_vector_type(4))) float f32x4;

__device__ __forceinline__ unsigned short f2bf_rne(float f) {
    unsigned int u = __float_as_uint(f);
    u += 0x7fffu + ((u >> 16) & 1u);
    return (unsigned short)(u >> 16);
}

// ---------------- zero ----------------
__global__ __launch_bounds__(256) void zero_kernel(int* __restrict__ p, int n) {
    int i = blockIdx.x * 256 + threadIdx.x;
    if (i < n) p[i] = 0;
}

// ---------------- convert fp32 -> packed bf16 ----------------
__global__ __launch_bounds__(256) void convert_bf16_kernel(const float4* __restrict__ in,
                                                           uint2* __restrict__ out, int n4) {
    int i = blockIdx.x * 256 + threadIdx.x;
    if (i >= n4) return;
    float4 v = in[i];
    uint2 o;
    o.x = (unsigned)f2bf_rne(v.x) | ((unsigned)f2bf_rne(v.y) << 16);
    o.y = (unsigned)f2bf_rne(v.z) | ((unsigned)f2bf_rne(v.w) << 16);
    out[i] = o;
}

// ---------------- histogram of dst ----------------
__global__ __launch_bounds__(256) void hist_kernel(const int* __restrict__ dst,
                                                   int* __restrict__ cnt, int nE) {
    int e = blockIdx.x * 256 + threadIdx.x;
    if (e < nE) atomicAdd(&cnt[dst[e]], 1);
}

// ---------------- scan ----------------
__global__ __launch_bounds__(256) void scan1_kernel(const int* __restrict__ cnt,
                                                    int* __restrict__ partial, int n) {
    __shared__ int s[256];
    int t = threadIdx.x;
    int i = blockIdx.x * 256 + t;
    s[t] = (i < n) ? cnt[i] : 0;
    __syncthreads();
    for (int off = 128; off > 0; off >>= 1) {
        if (t < off) s[t] += s[t + off];
        __syncthreads();
    }
    if (t == 0) partial[blockIdx.x] = s[0];
}

// parallel exclusive scan of the (<=512) block partials, single block
__global__ __launch_bounds__(512) void scan2_kernel(int* __restrict__ partial, int nb,
                                                    int* __restrict__ rowptr) {
    __shared__ int s[512];
    int t = threadIdx.x;
    int v = (t < nb) ? partial[t] : 0;
    s[t] = v;
    __syncthreads();
    for (int off = 1; off < 512; off <<= 1) {
        int add = (t >= off) ? s[t - off] : 0;
        __syncthreads();
        s[t] += add;
        __syncthreads();
    }
    if (t < nb) partial[t] = s[t] - v;            // exclusive
    if (t == 511) rowptr[NNODES] = s[511];        // total == NEDGES
}

__global__ __launch_bounds__(256) void scan3_kernel(const int* __restrict__ cnt,
                                                    const int* __restrict__ partial,
                                                    int* __restrict__ rowptr, int n) {
    __shared__ int s[256];
    int t = threadIdx.x;
    int i = blockIdx.x * 256 + t;
    int val = (i < n) ? cnt[i] : 0;
    s[t] = val;
    __syncthreads();
    for (int off = 1; off < 256; off <<= 1) {
        int add = (t >= off) ? s[t - off] : 0;
        __syncthreads();
        s[t] += add;
        __syncthreads();
    }
    if (i < n) rowptr[i] = partial[blockIdx.x] + s[t] - val;
}

// ---------------- scatter edges into dst-sorted order ----------------
__global__ __launch_bounds__(256) void scatter_edges_kernel(
        const int* __restrict__ src, const int* __restrict__ dst,
        const int* __restrict__ rowptr, int* __restrict__ fill,
        int* __restrict__ sortedSrc, int nE) {
    int e = blockIdx.x * 256 + threadIdx.x;
    if (e >= nE) return;
    int d = dst[e];
    int pos = rowptr[d] + atomicAdd(&fill[d], 1);
    sortedSrc[pos] = src[e];
}

// ---------------- aggregation v2: 4 edges per load, one wave per node ----------
// lane = (grp=lane>>4)*16 + c16; lane covers 16B chunk c16 of edge grp's row.
// One bpermute + one dwordx4 covers 4 edges; unroll-by-2 keeps 2 loads in flight.
// Padding is idempotent (duplicate last edge id; max unaffected).
__global__ __launch_bounds__(256) void aggregate_max_bf16_v2(
        const uint4* __restrict__ xb,          // [M][16] uint4 = 128 bf16/row
        const int* __restrict__ rowptr,
        const int* __restrict__ sortedSrc,
        uint4* __restrict__ aggrb,             // [M][16] uint4
        int nN) {
    const int wave = threadIdx.x >> 6;
    const int lane = threadIdx.x & 63;
    const int n = blockIdx.x * 4 + wave;
    if (n >= nN) return;
    const int beg = rowptr[n];
    const int end = rowptr[n + 1];
    const int grp = lane >> 4;
    const int c16 = lane & 15;

    if (end == beg) {                           // isolated node -> 0
        if (lane < 16) {
            uint4 z; z.x = z.y = z.z = z.w = 0u;
            aggrb[(size_t)n * 16 + lane] = z;
        }
        return;
    }

    float acc[8];
#pragma unroll
    for (int i = 0; i < 8; ++i) acc[i] = -INFINITY;

    const int last = end - 1;
    for (int base = beg; base < end; base += 64) {
        int idx = base + lane;
        int myid = sortedSrc[idx <= last ? idx : last];   // dup-pad batch
        int m = end - base; if (m > 64) m = 64;
        for (int j = 0; j < m; j += 8) {
            int s0 = __shfl(myid, j + grp);
            int s1 = __shfl(myid, j + 4 + grp);
            uint4 p0 = xb[(size_t)s0 * 16 + c16];
            uint4 p1 = xb[(size_t)s1 * 16 + c16];
            unsigned int u[8] = {p0.x, p0.y, p0.z, p0.w, p1.x, p1.y, p1.z, p1.w};
#pragma unroll
            for (int q = 0; q < 8; ++q) {
                float fe = __uint_as_float(u[q] << 16);
                float fo = __uint_as_float(u[q] & 0xffff0000u);
                int c = (q & 3) * 2;
                acc[c]     = fmaxf(acc[c],     fe);
                acc[c + 1] = fmaxf(acc[c + 1], fo);
            }
        }
    }
    // merge the 4 edge-groups (lanes differing in bits 4,5)
#pragma unroll
    for (int i = 0; i < 8; ++i) {
        float v = acc[i];
        v = fmaxf(v, __shfl_xor(v, 16));
        v = fmaxf(v, __shfl_xor(v, 32));
        acc[i] = v;
    }
    if (lane < 16) {
        uint4 o;   // bf16 values are exact -> truncation repack is exact
        o.x = (__float_as_uint(acc[1]) & 0xffff0000u) | (__float_as_uint(acc[0]) >> 16);
        o.y = (__float_as_uint(acc[3]) & 0xffff0000u) | (__float_as_uint(acc[2]) >> 16);
        o.z = (__float_as_uint(acc[5]) & 0xffff0000u) | (__float_as_uint(acc[4]) >> 16);
        o.w = (__float_as_uint(acc[7]) & 0xffff0000u) | (__float_as_uint(acc[6]) >> 16);
        aggrb[(size_t)n * 16 + c16] = o;
    }
}

// ---------------- MFMA bf16 fused SAGE GEMM ----------------
template<int BN, bool RELU, typename OutT>
__global__ __launch_bounds__(256) void sage_gemm_mfma(
        const unsigned short* __restrict__ Aagg,   // [M][128] bf16
        const unsigned short* __restrict__ Aroot,  // [M][128] bf16
        const float* __restrict__ Wl,              // [128][BN] f32
        const float* __restrict__ Wr,              // [128][BN] f32
        const float* __restrict__ bias,            // [BN] f32
        OutT* __restrict__ C,                      // [M][BN]
        int M) {
    constexpr int KP = 136;
    constexpr int NT = BN / 16;
    __shared__ __align__(16) unsigned short Bs[BN * KP];

    const int tid = threadIdx.x;
    const int wave = tid >> 6;
    const int lane = tid & 63;
    const int quad = lane >> 4;
    const int mrow = lane & 15;

    const int rowA = blockIdx.x * 64 + wave * 16 + mrow;
    const int rowAc = (rowA < M) ? rowA : 0;
    const int rowD = blockIdx.x * 64 + wave * 16 + quad * 4;

    f32x4 acc[NT];
#pragma unroll
    for (int nt = 0; nt < NT; ++nt) acc[nt] = (f32x4){0.f, 0.f, 0.f, 0.f};

    for (int half = 0; half < 2; ++half) {
        const float* W = half ? Wr : Wl;
        const unsigned short* Asrc = half ? Aroot : Aagg;
        __syncthreads();
        for (int i = tid; i < BN * 128; i += 256) {
            int n = i % BN;
            int k = i / BN;
            Bs[n * KP + k] = f2bf_rne(W[k * BN + n]);
        }
        __syncthreads();
#pragma unroll
        for (int kt = 0; kt < 4; ++kt) {
            bf16x8 a = *(const bf16x8*)(Asrc + (size_t)rowAc * 128 + kt * 32 + quad * 8);
#pragma unroll
            for (int nt = 0; nt < NT; ++nt) {
                bf16x8 b = *(const bf16x8*)(&Bs[(nt * 16 + mrow) * KP + kt * 32 + quad * 8]);
                acc[nt] = __builtin_amdgcn_mfma_f32_16x16x32_bf16(a, b, acc[nt], 0, 0, 0);
            }
        }
    }

#pragma unroll
    for (int nt = 0; nt < NT; ++nt) {
        int col = nt * 16 + mrow;
        float bv = bias[col];
#pragma unroll
        for (int r = 0; r < 4; ++r) {
            int grow = rowD + r;
            if (grow < M) {
                float v = acc[nt][r] + bv;
                if (RELU) v = fmaxf(v, 0.0f);
                if constexpr (sizeof(OutT) == 2)
                    C[(size_t)grow * BN + col] = (OutT)f2bf_rne(v);
                else
                    C[(size_t)grow * BN + col] = (OutT)v;
            }
        }
    }
}

extern "C" void kernel_launch(void* const* d_in, const int* in_sizes, int n_in,
                              void* d_out, int out_size, void* d_ws, size_t ws_size,
                              hipStream_t stream) {
    const float* x   = (const float*)d_in[0];
    const int*   ei  = (const int*)d_in[1];
    const float* W1l = (const float*)d_in[2];
    const float* b1l = (const float*)d_in[3];
    const float* W1r = (const float*)d_in[4];
    const float* W2l = (const float*)d_in[5];
    const float* b2l = (const float*)d_in[6];
    const float* W2r = (const float*)d_in[7];
    float* out = (float*)d_out;

    const int* src = ei;
    const int* dst = ei + NEDGES;

    // ---- workspace layout ----
    char* ws = (char*)d_ws;
    unsigned short* xb    = (unsigned short*)ws; ws += (size_t)NNODES * 128 * 2;
    unsigned short* hb    = (unsigned short*)ws; ws += (size_t)NNODES * 128 * 2;
    unsigned short* aggrb = (unsigned short*)ws; ws += (size_t)NNODES * 128 * 2;
    int* sortedSrc = (int*)ws;  ws += (size_t)NEDGES * 4;
    int* rowptr    = (int*)ws;  ws += (size_t)(NNODES + 1) * 4;
    int* cnt       = (int*)ws;  ws += (size_t)NNODES * 4;
    int* fill      = (int*)ws;  ws += (size_t)NNODES * 4;
    int* partial   = (int*)ws;  ws += (size_t)NB_SCAN * 4;

    const int gE = (NEDGES + 255) / 256;
    const int gN = NB_SCAN;
    const int gAgg = (NNODES + 3) / 4;
    const int gGemm = (NNODES + 63) / 64;
    const int n4 = NNODES * 128 / 4;

    // ---- build dst-sorted CSR + bf16 copy of x ----
    zero_kernel<<<(2 * NNODES + 255) / 256, 256, 0, stream>>>(cnt, 2 * NNODES);
    convert_bf16_kernel<<<(n4 + 255) / 256, 256, 0, stream>>>((const float4*)x, (uint2*)xb, n4);
    hist_kernel<<<gE, 256, 0, stream>>>(dst, cnt, NEDGES);
    scan1_kernel<<<gN, 256, 0, stream>>>(cnt, partial, NNODES);
    scan2_kernel<<<1, 512, 0, stream>>>(partial, NB_SCAN, rowptr);
    scan3_kernel<<<gN, 256, 0, stream>>>(cnt, partial, rowptr, NNODES);
    scatter_edges_kernel<<<gE, 256, 0, stream>>>(src, dst, rowptr, fill, sortedSrc, NEDGES);

    // ---- layer 1 ----
    aggregate_max_bf16_v2<<<gAgg, 256, 0, stream>>>((const uint4*)xb, rowptr, sortedSrc,
                                                    (uint4*)aggrb, NNODES);
    sage_gemm_mfma<128, true, unsigned short><<<gGemm, 256, 0, stream>>>(
        aggrb, xb, W1l, W1r, b1l, hb, NNODES);
    // ---- layer 2 ----
    aggregate_max_bf16_v2<<<gAgg, 256, 0, stream>>>((const uint4*)hb, rowptr, sortedSrc,
                                                    (uint4*)aggrb, NNODES);
    sage_gemm_mfma<64, false, float><<<gGemm, 256, 0, stream>>>(
        aggrb, hb, W2l, W2r, b2l, out, NNODES);
}

// Round 5
// 311.578 us; speedup vs baseline: 20.5892x; 1.4193x over previous
//
#include <hip/hip_runtime.h>
#include <cstdint>
#include <cmath>

#define NNODES 100000
#define NEDGES 1600000
#define NBKT   196          // ceil(NNODES / 512); bucket = dst >> 9
#define CAP    9216         // per-bucket capacity: mean 8192 + ~11 sigma
#define BIN_CHUNK 4096

typedef __attribute__((ext_vector_type(8))) __bf16 bf16x8;
typedef __attribute__((ext_vector_type(4))) float f32x4;

__device__ __forceinline__ unsigned short f2bf_rne(float f) {
    unsigned int u = __float_as_uint(f);
    u += 0x7fffu + ((u >> 16) & 1u);
    return (unsigned short)(u >> 16);
}

// ---------------- zero (tiny: bucket fill counters) ----------------
__global__ __launch_bounds__(256) void zero_kernel(int* __restrict__ p, int n) {
    int i = blockIdx.x * 256 + threadIdx.x;
    if (i < n) p[i] = 0;
}

// ---------------- convert fp32 -> packed bf16 ----------------
__global__ __launch_bounds__(256) void convert_bf16_kernel(const float4* __restrict__ in,
                                                           uint2* __restrict__ out, int n4) {
    int i = blockIdx.x * 256 + threadIdx.x;
    if (i >= n4) return;
    float4 v = in[i];
    uint2 o;
    o.x = (unsigned)f2bf_rne(v.x) | ((unsigned)f2bf_rne(v.y) << 16);
    o.y = (unsigned)f2bf_rne(v.z) | ((unsigned)f2bf_rne(v.w) << 16);
    out[i] = o;
}

// ---------------- pass A: bin edges by dst>>9, LDS-local sort, coalesced out ---
// entry = (dst&511)<<17 | src   (src < 2^17)
__global__ __launch_bounds__(256) void bin_kernel(
        const int* __restrict__ src, const int* __restrict__ dst,
        unsigned int* __restrict__ binArr, int* __restrict__ bucketFill, int nE) {
    __shared__ unsigned int stage[BIN_CHUNK];
    __shared__ unsigned char bof[BIN_CHUNK];
    __shared__ int cnt[256], cstart[256], cfill[256], gbase[256];
    const int tid = threadIdx.x;
    const int blockStart = blockIdx.x * BIN_CHUNK;
    const int chunkN = min(BIN_CHUNK, nE - blockStart);

    cnt[tid] = 0;
    __syncthreads();

    int myd[16], mys[16];
#pragma unroll
    for (int i = 0; i < 16; ++i) {
        int idx = i * 256 + tid;
        if (idx < chunkN) {
            myd[i] = dst[blockStart + idx];
            mys[i] = src[blockStart + idx];
            atomicAdd(&cnt[myd[i] >> 9], 1);
        }
    }
    __syncthreads();
    // in-place inclusive scan of cnt -> exclusive starts
    int v = cnt[tid];
    for (int off = 1; off < 256; off <<= 1) {
        int add = (tid >= off) ? cnt[tid - off] : 0;
        __syncthreads();
        cnt[tid] += add;
        __syncthreads();
    }
    cstart[tid] = cnt[tid] - v;
    cfill[tid] = cnt[tid] - v;
    if (tid < NBKT && v > 0) gbase[tid] = atomicAdd(&bucketFill[tid], v);
    __syncthreads();
    // local counting sort into stage
#pragma unroll
    for (int i = 0; i < 16; ++i) {
        int idx = i * 256 + tid;
        if (idx < chunkN) {
            int b = myd[i] >> 9;
            int p = atomicAdd(&cfill[b], 1);
            stage[p] = ((unsigned)(myd[i] & 511) << 17) | (unsigned)mys[i];
            bof[p] = (unsigned char)b;
        }
    }
    __syncthreads();
    // bucket-contiguous copy out (runs of ~chunk/NBKT edges -> coalesced)
#pragma unroll
    for (int i = 0; i < 16; ++i) {
        int idx = i * 256 + tid;
        if (idx < chunkN) {
            int b = bof[idx];
            int slot = gbase[b] + (idx - cstart[b]);
            if (slot < CAP) binArr[(size_t)b * CAP + slot] = stage[idx];
        }
    }
}

// ---------------- pass B: per-bucket CSR build, all in LDS ----------------
__global__ __launch_bounds__(512) void build_csr_kernel(
        const unsigned int* __restrict__ binArr, const int* __restrict__ bucketFill,
        unsigned int* __restrict__ sortedSrc,
        int* __restrict__ rowBeg, int* __restrict__ rowEnd) {
    __shared__ unsigned int stage[CAP];      // 36 KB
    __shared__ int ncnt[512], nstart[512];
    const int b = blockIdx.x;
    const int t = threadIdx.x;
    const int cnt_b = min(bucketFill[b], CAP);

    ncnt[t] = 0;
    __syncthreads();
    for (int i = t; i < cnt_b; i += 512) {
        unsigned int e = binArr[(size_t)b * CAP + i];
        stage[i] = e;
        atomicAdd(&ncnt[e >> 17], 1);
    }
    __syncthreads();
    int v = ncnt[t];
    for (int off = 1; off < 512; off <<= 1) {
        int add = (t >= off) ? ncnt[t - off] : 0;
        __syncthreads();
        ncnt[t] += add;
        __syncthreads();
    }
    int start = ncnt[t] - v;
    nstart[t] = start;            // becomes running fill below
    int n = (b << 9) + t;
    if (n < NNODES) {
        rowBeg[n] = b * CAP + start;
        rowEnd[n] = b * CAP + start + v;
    }
    __syncthreads();
    for (int i = t; i < cnt_b; i += 512) {
        unsigned int e = stage[i];
        int p = atomicAdd(&nstart[e >> 17], 1);
        sortedSrc[(size_t)b * CAP + p] = e & 0x1FFFFu;   // 36 KB window: L1-resident
    }
}

// ---------------- aggregation: 4 edges per load, one wave per node ----------
__global__ __launch_bounds__(256) void aggregate_max_bf16_v2(
        const uint4* __restrict__ xb,                 // [M][16] uint4 = 128 bf16/row
        const int* __restrict__ rowBeg,
        const int* __restrict__ rowEnd,
        const unsigned int* __restrict__ sortedSrc,
        uint4* __restrict__ aggrb, int nN) {
    const int wave = threadIdx.x >> 6;
    const int lane = threadIdx.x & 63;
    const int n = blockIdx.x * 4 + wave;
    if (n >= nN) return;
    const int beg = rowBeg[n];
    const int end = rowEnd[n];
    const int grp = lane >> 4;
    const int c16 = lane & 15;

    if (end == beg) {                           // isolated node -> 0
        if (lane < 16) {
            uint4 z; z.x = z.y = z.z = z.w = 0u;
            aggrb[(size_t)n * 16 + lane] = z;
        }
        return;
    }

    float acc[8];
#pragma unroll
    for (int i = 0; i < 8; ++i) acc[i] = -INFINITY;

    const int last = end - 1;
    for (int base = beg; base < end; base += 64) {
        int idx = base + lane;
        int myid = (int)sortedSrc[idx <= last ? idx : last];   // dup-pad batch
        int m = end - base; if (m > 64) m = 64;
        for (int j = 0; j < m; j += 8) {
            int s0 = __shfl(myid, j + grp);
            int s1 = __shfl(myid, j + 4 + grp);
            uint4 p0 = xb[(size_t)s0 * 16 + c16];
            uint4 p1 = xb[(size_t)s1 * 16 + c16];
            unsigned int u[8] = {p0.x, p0.y, p0.z, p0.w, p1.x, p1.y, p1.z, p1.w};
#pragma unroll
            for (int q = 0; q < 8; ++q) {
                float fe = __uint_as_float(u[q] << 16);
                float fo = __uint_as_float(u[q] & 0xffff0000u);
                int c = (q & 3) * 2;
                acc[c]     = fmaxf(acc[c],     fe);
                acc[c + 1] = fmaxf(acc[c + 1], fo);
            }
        }
    }
#pragma unroll
    for (int i = 0; i < 8; ++i) {
        float v = acc[i];
        v = fmaxf(v, __shfl_xor(v, 16));
        v = fmaxf(v, __shfl_xor(v, 32));
        acc[i] = v;
    }
    if (lane < 16) {
        uint4 o;   // bf16 values are exact -> truncation repack is exact
        o.x = (__float_as_uint(acc[1]) & 0xffff0000u) | (__float_as_uint(acc[0]) >> 16);
        o.y = (__float_as_uint(acc[3]) & 0xffff0000u) | (__float_as_uint(acc[2]) >> 16);
        o.z = (__float_as_uint(acc[5]) & 0xffff0000u) | (__float_as_uint(acc[4]) >> 16);
        o.w = (__float_as_uint(acc[7]) & 0xffff0000u) | (__float_as_uint(acc[6]) >> 16);
        aggrb[(size_t)n * 16 + c16] = o;
    }
}

// ---------------- MFMA bf16 fused SAGE GEMM ----------------
template<int BN, bool RELU, typename OutT>
__global__ __launch_bounds__(256) void sage_gemm_mfma(
        const unsigned short* __restrict__ Aagg,   // [M][128] bf16
        const unsigned short* __restrict__ Aroot,  // [M][128] bf16
        const float* __restrict__ Wl,              // [128][BN] f32
        const float* __restrict__ Wr,              // [128][BN] f32
        const float* __restrict__ bias,            // [BN] f32
        OutT* __restrict__ C,                      // [M][BN]
        int M) {
    constexpr int KP = 136;
    constexpr int NT = BN / 16;
    __shared__ __align__(16) unsigned short Bs[BN * KP];

    const int tid = threadIdx.x;
    const int wave = tid >> 6;
    const int lane = tid & 63;
    const int quad = lane >> 4;
    const int mrow = lane & 15;

    const int rowA = blockIdx.x * 64 + wave * 16 + mrow;
    const int rowAc = (rowA < M) ? rowA : 0;
    const int rowD = blockIdx.x * 64 + wave * 16 + quad * 4;

    f32x4 acc[NT];
#pragma unroll
    for (int nt = 0; nt < NT; ++nt) acc[nt] = (f32x4){0.f, 0.f, 0.f, 0.f};

    for (int half = 0; half < 2; ++half) {
        const float* W = half ? Wr : Wl;
        const unsigned short* Asrc = half ? Aroot : Aagg;
        __syncthreads();
        for (int i = tid; i < BN * 128; i += 256) {
            int n = i % BN;
            int k = i / BN;
            Bs[n * KP + k] = f2bf_rne(W[k * BN + n]);
        }
        __syncthreads();
#pragma unroll
        for (int kt = 0; kt < 4; ++kt) {
            bf16x8 a = *(const bf16x8*)(Asrc + (size_t)rowAc * 128 + kt * 32 + quad * 8);
#pragma unroll
            for (int nt = 0; nt < NT; ++nt) {
                bf16x8 b = *(const bf16x8*)(&Bs[(nt * 16 + mrow) * KP + kt * 32 + quad * 8]);
                acc[nt] = __builtin_amdgcn_mfma_f32_16x16x32_bf16(a, b, acc[nt], 0, 0, 0);
            }
        }
    }

#pragma unroll
    for (int nt = 0; nt < NT; ++nt) {
        int col = nt * 16 + mrow;
        float bv = bias[col];
#pragma unroll
        for (int r = 0; r < 4; ++r) {
            int grow = rowD + r;
            if (grow < M) {
                float v = acc[nt][r] + bv;
                if (RELU) v = fmaxf(v, 0.0f);
                if constexpr (sizeof(OutT) == 2)
                    C[(size_t)grow * BN + col] = (OutT)f2bf_rne(v);
                else
                    C[(size_t)grow * BN + col] = (OutT)v;
            }
        }
    }
}

extern "C" void kernel_launch(void* const* d_in, const int* in_sizes, int n_in,
                              void* d_out, int out_size, void* d_ws, size_t ws_size,
                              hipStream_t stream) {
    const float* x   = (const float*)d_in[0];
    const int*   ei  = (const int*)d_in[1];
    const float* W1l = (const float*)d_in[2];
    const float* b1l = (const float*)d_in[3];
    const float* W1r = (const float*)d_in[4];
    const float* W2l = (const float*)d_in[5];
    const float* b2l = (const float*)d_in[6];
    const float* W2r = (const float*)d_in[7];
    float* out = (float*)d_out;

    const int* src = ei;
    const int* dst = ei + NEDGES;

    // ---- workspace layout ----
    char* ws = (char*)d_ws;
    unsigned short* xb    = (unsigned short*)ws; ws += (size_t)NNODES * 128 * 2;  // 25.6 MB
    unsigned short* hb    = (unsigned short*)ws; ws += (size_t)NNODES * 128 * 2;  // 25.6 MB
    unsigned short* aggrb = (unsigned short*)ws; ws += (size_t)NNODES * 128 * 2;  // 25.6 MB
    unsigned int* binArr    = (unsigned int*)ws; ws += (size_t)NBKT * CAP * 4;    // 7.2 MB
    unsigned int* sortedSrc = (unsigned int*)ws; ws += (size_t)NBKT * CAP * 4;    // 7.2 MB
    int* rowBeg     = (int*)ws; ws += (size_t)NNODES * 4;
    int* rowEnd     = (int*)ws; ws += (size_t)NNODES * 4;
    int* bucketFill = (int*)ws; ws += 256 * 4;

    const int gAgg = (NNODES + 3) / 4;
    const int gGemm = (NNODES + 63) / 64;
    const int n4 = NNODES * 128 / 4;
    const int gBin = (NEDGES + BIN_CHUNK - 1) / BIN_CHUNK;   // 391

    // ---- build bucketed CSR + bf16 copy of x ----
    zero_kernel<<<1, 256, 0, stream>>>(bucketFill, 256);
    convert_bf16_kernel<<<(n4 + 255) / 256, 256, 0, stream>>>((const float4*)x, (uint2*)xb, n4);
    bin_kernel<<<gBin, 256, 0, stream>>>(src, dst, binArr, bucketFill, NEDGES);
    build_csr_kernel<<<NBKT, 512, 0, stream>>>(binArr, bucketFill, sortedSrc, rowBeg, rowEnd);

    // ---- layer 1 ----
    aggregate_max_bf16_v2<<<gAgg, 256, 0, stream>>>((const uint4*)xb, rowBeg, rowEnd, sortedSrc,
                                                    (uint4*)aggrb, NNODES);
    sage_gemm_mfma<128, true, unsigned short><<<gGemm, 256, 0, stream>>>(
        aggrb, xb, W1l, W1r, b1l, hb, NNODES);
    // ---- layer 2 ----
    aggregate_max_bf16_v2<<<gAgg, 256, 0, stream>>>((const uint4*)hb, rowBeg, rowEnd, sortedSrc,
                                                    (uint4*)aggrb, NNODES);
    sage_gemm_mfma<64, false, float><<<gGemm, 256, 0, stream>>>(
        aggrb, hb, W2l, W2r, b2l, out, NNODES);
}

// Round 6
// 306.520 us; speedup vs baseline: 20.9289x; 1.0165x over previous
//
#include <hip/hip_runtime.h>
#include <cstdint>
#include <cmath>

#define NNODES 100000
#define NEDGES 1600000
#define NBKT   196          // ceil(NNODES / 512); bucket = dst >> 9
#define CAP    9216         // per-bucket capacity: mean 8192 + ~11 sigma
#define BIN_CHUNK 4096
#define KP 136              // LDS/global W leading dim (bf16 elems), 16B-aligned pad

typedef __attribute__((ext_vector_type(8))) __bf16 bf16x8;
typedef __attribute__((ext_vector_type(4))) float f32x4;
typedef short v2s __attribute__((ext_vector_type(2)));

__device__ __forceinline__ unsigned short f2bf_rne(float f) {
    unsigned int u = __float_as_uint(f);
    u += 0x7fffu + ((u >> 16) & 1u);
    return (unsigned short)(u >> 16);
}

// involutive monotone map: bf16 float order <-> signed i16 order (per packed half)
__device__ __forceinline__ unsigned encdec(unsigned u) {
    return u ^ (((u & 0x80008000u) >> 15) * 0x7FFFu);
}

__device__ __forceinline__ unsigned pkmax(unsigned a, unsigned b) {
    v2s r = __builtin_elementwise_max(__builtin_bit_cast(v2s, a), __builtin_bit_cast(v2s, b));
    return __builtin_bit_cast(unsigned, r);
}

// ---------------- zero (tiny: bucket fill counters) ----------------
__global__ __launch_bounds__(256) void zero_kernel(int* __restrict__ p, int n) {
    int i = blockIdx.x * 256 + threadIdx.x;
    if (i < n) p[i] = 0;
}

// ---------------- convert fp32 -> packed ENCODED bf16 ----------------
__global__ __launch_bounds__(256) void convert_encode_kernel(const float4* __restrict__ in,
                                                             uint2* __restrict__ out, int n4) {
    int i = blockIdx.x * 256 + threadIdx.x;
    if (i >= n4) return;
    float4 v = in[i];
    uint2 o;
    o.x = encdec((unsigned)f2bf_rne(v.x) | ((unsigned)f2bf_rne(v.y) << 16));
    o.y = encdec((unsigned)f2bf_rne(v.z) | ((unsigned)f2bf_rne(v.w) << 16));
    out[i] = o;
}

// ---------------- weights: f32 [K][N] -> bf16 transposed [N][KP] ----------------
__global__ __launch_bounds__(256) void convert_weights_kernel(
        const float* __restrict__ W1l, const float* __restrict__ W1r,
        const float* __restrict__ W2l, const float* __restrict__ W2r,
        unsigned short* __restrict__ T1l, unsigned short* __restrict__ T1r,
        unsigned short* __restrict__ T2l, unsigned short* __restrict__ T2r) {
    int i = blockIdx.x * 256 + threadIdx.x;
    if (i < 128 * 128) {
        int k = i >> 7, n = i & 127;
        T1l[n * KP + k] = f2bf_rne(W1l[i]);
        T1r[n * KP + k] = f2bf_rne(W1r[i]);
    }
    if (i < 128 * 64) {
        int k = i >> 6, n = i & 63;
        T2l[n * KP + k] = f2bf_rne(W2l[i]);
        T2r[n * KP + k] = f2bf_rne(W2r[i]);
    }
}

// ---------------- pass A: bin edges by dst>>9 ----------------
// entry = (dst&511)<<17 | src   (src < 2^17)
__global__ __launch_bounds__(256) void bin_kernel(
        const int* __restrict__ src, const int* __restrict__ dst,
        unsigned int* __restrict__ binArr, int* __restrict__ bucketFill, int nE) {
    __shared__ unsigned int stage[BIN_CHUNK];
    __shared__ unsigned char bof[BIN_CHUNK];
    __shared__ int cnt[256], cstart[256], cfill[256], gbase[256];
    const int tid = threadIdx.x;
    const int blockStart = blockIdx.x * BIN_CHUNK;
    const int chunkN = min(BIN_CHUNK, nE - blockStart);

    cnt[tid] = 0;
    __syncthreads();

    int myd[16], mys[16];
#pragma unroll
    for (int i = 0; i < 16; ++i) {
        int idx = i * 256 + tid;
        if (idx < chunkN) {
            myd[i] = dst[blockStart + idx];
            mys[i] = src[blockStart + idx];
            atomicAdd(&cnt[myd[i] >> 9], 1);
        }
    }
    __syncthreads();
    int v = cnt[tid];
    for (int off = 1; off < 256; off <<= 1) {
        int add = (tid >= off) ? cnt[tid - off] : 0;
        __syncthreads();
        cnt[tid] += add;
        __syncthreads();
    }
    cstart[tid] = cnt[tid] - v;
    cfill[tid] = cnt[tid] - v;
    if (tid < NBKT && v > 0) gbase[tid] = atomicAdd(&bucketFill[tid], v);
    __syncthreads();
#pragma unroll
    for (int i = 0; i < 16; ++i) {
        int idx = i * 256 + tid;
        if (idx < chunkN) {
            int b = myd[i] >> 9;
            int p = atomicAdd(&cfill[b], 1);
            stage[p] = ((unsigned)(myd[i] & 511) << 17) | (unsigned)mys[i];
            bof[p] = (unsigned char)b;
        }
    }
    __syncthreads();
#pragma unroll
    for (int i = 0; i < 16; ++i) {
        int idx = i * 256 + tid;
        if (idx < chunkN) {
            int b = bof[idx];
            int slot = gbase[b] + (idx - cstart[b]);
            if (slot < CAP) binArr[(size_t)b * CAP + slot] = stage[idx];
        }
    }
}

// ---------------- pass B: per-bucket CSR build, all in LDS ----------------
__global__ __launch_bounds__(512) void build_csr_kernel(
        const unsigned int* __restrict__ binArr, const int* __restrict__ bucketFill,
        unsigned int* __restrict__ sortedSrc,
        int* __restrict__ rowBeg, int* __restrict__ rowEnd) {
    __shared__ unsigned int stage[CAP];      // 36 KB
    __shared__ int ncnt[512], nstart[512];
    const int b = blockIdx.x;
    const int t = threadIdx.x;
    const int cnt_b = min(bucketFill[b], CAP);

    ncnt[t] = 0;
    __syncthreads();
    for (int i = t; i < cnt_b; i += 512) {
        unsigned int e = binArr[(size_t)b * CAP + i];
        stage[i] = e;
        atomicAdd(&ncnt[e >> 17], 1);
    }
    __syncthreads();
    int v = ncnt[t];
    for (int off = 1; off < 512; off <<= 1) {
        int add = (t >= off) ? ncnt[t - off] : 0;
        __syncthreads();
        ncnt[t] += add;
        __syncthreads();
    }
    int start = ncnt[t] - v;
    nstart[t] = start;
    int n = (b << 9) + t;
    if (n < NNODES) {
        rowBeg[n] = b * CAP + start;
        rowEnd[n] = b * CAP + start + v;
    }
    __syncthreads();
    for (int i = t; i < cnt_b; i += 512) {
        unsigned int e = stage[i];
        int p = atomicAdd(&nstart[e >> 17], 1);
        sortedSrc[(size_t)b * CAP + p] = e & 0x1FFFFu;
    }
}

// ---------------- aggregation: packed i16 max on encoded rows ----------------
// lane = grp*16 + c16; lane covers 16B chunk c16 of edge grp's row.
// Input xe is ENCODED bf16; inner loop = pure v_pk_max_i16; decode on write.
__global__ __launch_bounds__(256) void aggregate_max_pk(
        const uint4* __restrict__ xe,                 // [M][16] uint4, encoded
        const int* __restrict__ rowBeg,
        const int* __restrict__ rowEnd,
        const unsigned int* __restrict__ sortedSrc,
        uint4* __restrict__ aggrb, int nN) {          // [M][16] uint4, PLAIN bf16
    const int wave = threadIdx.x >> 6;
    const int lane = threadIdx.x & 63;
    const int n = blockIdx.x * 4 + wave;
    if (n >= nN) return;
    const int beg = rowBeg[n];
    const int end = rowEnd[n];
    const int grp = lane >> 4;
    const int c16 = lane & 15;

    if (end == beg) {                           // isolated node -> 0
        if (lane < 16) {
            uint4 z; z.x = z.y = z.z = z.w = 0u;
            aggrb[(size_t)n * 16 + lane] = z;
        }
        return;
    }

    unsigned accp[4];
#pragma unroll
    for (int i = 0; i < 4; ++i) accp[i] = 0x80008000u;   // encoded-domain minimum

    const int last = end - 1;
    for (int base = beg; base < end; base += 64) {
        int idx = base + lane;
        int myid = (int)sortedSrc[idx <= last ? idx : last];   // dup-pad (max-idempotent)
        int m = end - base; if (m > 64) m = 64;
        for (int j = 0; j < m; j += 8) {
            int s0 = __shfl(myid, j + grp);
            int s1 = __shfl(myid, j + 4 + grp);
            uint4 p0 = xe[(size_t)s0 * 16 + c16];
            uint4 p1 = xe[(size_t)s1 * 16 + c16];
            accp[0] = pkmax(accp[0], p0.x);
            accp[1] = pkmax(accp[1], p0.y);
            accp[2] = pkmax(accp[2], p0.z);
            accp[3] = pkmax(accp[3], p0.w);
            accp[0] = pkmax(accp[0], p1.x);
            accp[1] = pkmax(accp[1], p1.y);
            accp[2] = pkmax(accp[2], p1.z);
            accp[3] = pkmax(accp[3], p1.w);
        }
    }
    // merge the 4 edge-groups (lanes differing in bits 4,5)
#pragma unroll
    for (int i = 0; i < 4; ++i) {
        unsigned v = accp[i];
        v = pkmax(v, (unsigned)__shfl_xor((int)v, 16));
        v = pkmax(v, (unsigned)__shfl_xor((int)v, 32));
        accp[i] = v;
    }
    if (lane < 16) {
        uint4 o;   // decode back to plain bf16
        o.x = encdec(accp[0]);
        o.y = encdec(accp[1]);
        o.z = encdec(accp[2]);
        o.w = encdec(accp[3]);
        aggrb[(size_t)n * 16 + c16] = o;
    }
}

// ---------------- MFMA bf16 fused SAGE GEMM ----------------
// Aagg: plain bf16. Aroot: ENCODED bf16 (decoded on fragment load).
// Wt*: pre-converted bf16, transposed [N][KP]; staged to LDS by uint4 memcpy.
// ENCOUT: write bf16 output encoded (feeds next layer's aggregation/root).
template<int BN, bool RELU, bool ENCOUT, typename OutT>
__global__ __launch_bounds__(256) void sage_gemm_mfma(
        const unsigned short* __restrict__ Aagg,   // [M][128] bf16 plain
        const unsigned short* __restrict__ Aroot,  // [M][128] bf16 ENCODED
        const unsigned short* __restrict__ Wtl,    // [BN][KP] bf16
        const unsigned short* __restrict__ Wtr,    // [BN][KP] bf16
        const float* __restrict__ bias,            // [BN] f32
        OutT* __restrict__ C,                      // [M][BN]
        int M) {
    constexpr int NT = BN / 16;
    __shared__ __align__(16) unsigned short Bs[BN * KP];

    const int tid = threadIdx.x;
    const int wave = tid >> 6;
    const int lane = tid & 63;
    const int quad = lane >> 4;
    const int mrow = lane & 15;

    const int rowA = blockIdx.x * 64 + wave * 16 + mrow;
    const int rowAc = (rowA < M) ? rowA : 0;
    const int rowD = blockIdx.x * 64 + wave * 16 + quad * 4;

    f32x4 acc[NT];
#pragma unroll
    for (int nt = 0; nt < NT; ++nt) acc[nt] = (f32x4){0.f, 0.f, 0.f, 0.f};

    for (int half = 0; half < 2; ++half) {
        const uint4* wsrc = (const uint4*)(half ? Wtr : Wtl);
        __syncthreads();
        for (int i = tid; i < BN * KP / 8; i += 256) ((uint4*)Bs)[i] = wsrc[i];
        __syncthreads();
#pragma unroll
        for (int kt = 0; kt < 4; ++kt) {
            bf16x8 a;
            if (half == 0) {
                a = *(const bf16x8*)(Aagg + (size_t)rowAc * 128 + kt * 32 + quad * 8);
            } else {
                uint4 t = *(const uint4*)(Aroot + (size_t)rowAc * 128 + kt * 32 + quad * 8);
                t.x = encdec(t.x); t.y = encdec(t.y); t.z = encdec(t.z); t.w = encdec(t.w);
                a = __builtin_bit_cast(bf16x8, t);
            }
#pragma unroll
            for (int nt = 0; nt < NT; ++nt) {
                bf16x8 b = *(const bf16x8*)(&Bs[(nt * 16 + mrow) * KP + kt * 32 + quad * 8]);
                acc[nt] = __builtin_amdgcn_mfma_f32_16x16x32_bf16(a, b, acc[nt], 0, 0, 0);
            }
        }
    }

#pragma unroll
    for (int nt = 0; nt < NT; ++nt) {
        int col = nt * 16 + mrow;
        float bv = bias[col];
#pragma unroll
        for (int r = 0; r < 4; ++r) {
            int grow = rowD + r;
            if (grow < M) {
                float v = acc[nt][r] + bv;
                if (RELU) v = fmaxf(v, 0.0f);
                if constexpr (ENCOUT) {
                    unsigned u = f2bf_rne(v);
                    u ^= ((u >> 15) & 1u) * 0x7FFFu;   // encode (sign-preserving)
                    C[(size_t)grow * BN + col] = (OutT)u;
                } else {
                    C[(size_t)grow * BN + col] = (OutT)v;
                }
            }
        }
    }
}

extern "C" void kernel_launch(void* const* d_in, const int* in_sizes, int n_in,
                              void* d_out, int out_size, void* d_ws, size_t ws_size,
                              hipStream_t stream) {
    const float* x   = (const float*)d_in[0];
    const int*   ei  = (const int*)d_in[1];
    const float* W1l = (const float*)d_in[2];
    const float* b1l = (const float*)d_in[3];
    const float* W1r = (const float*)d_in[4];
    const float* W2l = (const float*)d_in[5];
    const float* b2l = (const float*)d_in[6];
    const float* W2r = (const float*)d_in[7];
    float* out = (float*)d_out;

    const int* src = ei;
    const int* dst = ei + NEDGES;

    // ---- workspace layout (all 16B-aligned sizes) ----
    char* ws = (char*)d_ws;
    unsigned short* xe    = (unsigned short*)ws; ws += (size_t)NNODES * 128 * 2;  // 25.6 MB (encoded)
    unsigned short* he    = (unsigned short*)ws; ws += (size_t)NNODES * 128 * 2;  // 25.6 MB (encoded)
    unsigned short* aggrb = (unsigned short*)ws; ws += (size_t)NNODES * 128 * 2;  // 25.6 MB (plain)
    unsigned int* binArr    = (unsigned int*)ws; ws += (size_t)NBKT * CAP * 4;    // 7.2 MB
    unsigned int* sortedSrc = (unsigned int*)ws; ws += (size_t)NBKT * CAP * 4;    // 7.2 MB
    int* rowBeg     = (int*)ws; ws += (size_t)NNODES * 4;
    int* rowEnd     = (int*)ws; ws += (size_t)NNODES * 4;
    int* bucketFill = (int*)ws; ws += 256 * 4;
    unsigned short* T1l = (unsigned short*)ws; ws += 128 * KP * 2;
    unsigned short* T1r = (unsigned short*)ws; ws += 128 * KP * 2;
    unsigned short* T2l = (unsigned short*)ws; ws += 64 * KP * 2;
    unsigned short* T2r = (unsigned short*)ws; ws += 64 * KP * 2;

    const int gAgg = (NNODES + 3) / 4;
    const int gGemm = (NNODES + 63) / 64;
    const int n4 = NNODES * 128 / 4;
    const int gBin = (NEDGES + BIN_CHUNK - 1) / BIN_CHUNK;

    // ---- prep: bucketed CSR, encoded-bf16 x, transposed bf16 weights ----
    zero_kernel<<<1, 256, 0, stream>>>(bucketFill, 256);
    convert_weights_kernel<<<64, 256, 0, stream>>>(W1l, W1r, W2l, W2r, T1l, T1r, T2l, T2r);
    convert_encode_kernel<<<(n4 + 255) / 256, 256, 0, stream>>>((const float4*)x, (uint2*)xe, n4);
    bin_kernel<<<gBin, 256, 0, stream>>>(src, dst, binArr, bucketFill, NEDGES);
    build_csr_kernel<<<NBKT, 512, 0, stream>>>(binArr, bucketFill, sortedSrc, rowBeg, rowEnd);

    // ---- layer 1 ----
    aggregate_max_pk<<<gAgg, 256, 0, stream>>>((const uint4*)xe, rowBeg, rowEnd, sortedSrc,
                                               (uint4*)aggrb, NNODES);
    sage_gemm_mfma<128, true, true, unsigned short><<<gGemm, 256, 0, stream>>>(
        aggrb, xe, T1l, T1r, b1l, he, NNODES);
    // ---- layer 2 ----
    aggregate_max_pk<<<gAgg, 256, 0, stream>>>((const uint4*)he, rowBeg, rowEnd, sortedSrc,
                                               (uint4*)aggrb, NNODES);
    sage_gemm_mfma<64, false, false, float><<<gGemm, 256, 0, stream>>>(
        aggrb, he, T2l, T2r, b2l, out, NNODES);
}

// Round 7
// 304.185 us; speedup vs baseline: 21.0896x; 1.0077x over previous
//
#include <hip/hip_runtime.h>
#include <cstdint>

#define NNODES 100000
#define NEDGES 1600000
#define NBKT   196          // ceil(NNODES / 512); bucket = dst >> 9
#define CAP    9216         // per-bucket capacity: mean 8192 + ~11 sigma
#define BIN_CHUNK 4096
#define KP 136              // As / global-W leading dim (bf16), conflict-free b128
#define GBIN ((NEDGES + BIN_CHUNK - 1) / BIN_CHUNK)   // 391
#define GCVT (NNODES * 128 / 8 / 256)                 // 6250 (8 floats/thread)

typedef __attribute__((ext_vector_type(8))) __bf16 bf16x8;
typedef __attribute__((ext_vector_type(4))) float f32x4;
typedef short v2s __attribute__((ext_vector_type(2)));

__device__ __forceinline__ unsigned short f2bf_rne(float f) {
    unsigned int u = __float_as_uint(f);
    u += 0x7fffu + ((u >> 16) & 1u);
    return (unsigned short)(u >> 16);
}
// involutive monotone map: bf16 float order <-> signed i16 order (per packed half)
__device__ __forceinline__ unsigned encdec(unsigned u) {
    return u ^ (((u & 0x80008000u) >> 15) * 0x7FFFu);
}
__device__ __forceinline__ unsigned pkmax(unsigned a, unsigned b) {
    v2s r = __builtin_elementwise_max(__builtin_bit_cast(v2s, a), __builtin_bit_cast(v2s, b));
    return __builtin_bit_cast(unsigned, r);
}

// ---------------- prep1: zero bucketFill + transpose/convert weights ----------
__global__ __launch_bounds__(256) void prep1_kernel(
        const float* __restrict__ W1l, const float* __restrict__ W1r,
        const float* __restrict__ W2l, const float* __restrict__ W2r,
        unsigned short* __restrict__ T1l, unsigned short* __restrict__ T1r,
        unsigned short* __restrict__ T2l, unsigned short* __restrict__ T2r,
        int* __restrict__ bucketFill) {
    if (blockIdx.x == 64) { bucketFill[threadIdx.x] = 0; return; }
    int i = blockIdx.x * 256 + threadIdx.x;   // < 16384
    int k = i >> 7, n = i & 127;
    T1l[n * KP + k] = f2bf_rne(W1l[i]);
    T1r[n * KP + k] = f2bf_rne(W1r[i]);
    if (i < 128 * 64) {
        int k2 = i >> 6, n2 = i & 63;
        T2l[n2 * KP + k2] = f2bf_rne(W2l[i]);
        T2r[n2 * KP + k2] = f2bf_rne(W2r[i]);
    }
}

// ---------------- prep2: bin edges (blocks [0,GBIN)) + encode x (rest) --------
__global__ __launch_bounds__(256) void prep2_kernel(
        const int* __restrict__ src, const int* __restrict__ dst,
        unsigned int* __restrict__ binArr, int* __restrict__ bucketFill,
        const float4* __restrict__ xin, uint4* __restrict__ xeout, int nE) {
    if (blockIdx.x >= GBIN) {
        // encode: 8 floats -> 1 uint4 (8 bf16, encoded)
        int i = (blockIdx.x - GBIN) * 256 + threadIdx.x;  // < 1.6M
        float4 v0 = xin[(size_t)2 * i], v1 = xin[(size_t)2 * i + 1];
        uint4 o;
        o.x = encdec((unsigned)f2bf_rne(v0.x) | ((unsigned)f2bf_rne(v0.y) << 16));
        o.y = encdec((unsigned)f2bf_rne(v0.z) | ((unsigned)f2bf_rne(v0.w) << 16));
        o.z = encdec((unsigned)f2bf_rne(v1.x) | ((unsigned)f2bf_rne(v1.y) << 16));
        o.w = encdec((unsigned)f2bf_rne(v1.z) | ((unsigned)f2bf_rne(v1.w) << 16));
        xeout[i] = o;
        return;
    }
    // ---- bin: entry = (dst&511)<<17 | src ----
    __shared__ unsigned int stage[BIN_CHUNK];
    __shared__ unsigned char bof[BIN_CHUNK];
    __shared__ int cnt[256], cstart[256], cfill[256], gbase[256];
    const int tid = threadIdx.x;
    const int blockStart = blockIdx.x * BIN_CHUNK;
    const int chunkN = min(BIN_CHUNK, nE - blockStart);
    cnt[tid] = 0;
    __syncthreads();
    int myd[16], mys[16];
#pragma unroll
    for (int i = 0; i < 16; ++i) {
        int idx = i * 256 + tid;
        if (idx < chunkN) {
            myd[i] = dst[blockStart + idx];
            mys[i] = src[blockStart + idx];
            atomicAdd(&cnt[myd[i] >> 9], 1);
        }
    }
    __syncthreads();
    int v = cnt[tid];
    for (int off = 1; off < 256; off <<= 1) {
        int add = (tid >= off) ? cnt[tid - off] : 0;
        __syncthreads();
        cnt[tid] += add;
        __syncthreads();
    }
    cstart[tid] = cnt[tid] - v;
    cfill[tid] = cnt[tid] - v;
    if (tid < NBKT && v > 0) gbase[tid] = atomicAdd(&bucketFill[tid], v);
    __syncthreads();
#pragma unroll
    for (int i = 0; i < 16; ++i) {
        int idx = i * 256 + tid;
        if (idx < chunkN) {
            int b = myd[i] >> 9;
            int p = atomicAdd(&cfill[b], 1);
            stage[p] = ((unsigned)(myd[i] & 511) << 17) | (unsigned)mys[i];
            bof[p] = (unsigned char)b;
        }
    }
    __syncthreads();
#pragma unroll
    for (int i = 0; i < 16; ++i) {
        int idx = i * 256 + tid;
        if (idx < chunkN) {
            int b = bof[idx];
            int slot = gbase[b] + (idx - cstart[b]);
            if (slot < CAP) binArr[(size_t)b * CAP + slot] = stage[idx];
        }
    }
}

// ---------------- per-bucket CSR build, all in LDS ----------------
__global__ __launch_bounds__(512) void build_csr_kernel(
        const unsigned int* __restrict__ binArr, const int* __restrict__ bucketFill,
        unsigned int* __restrict__ sortedSrc,
        int* __restrict__ rowBeg, int* __restrict__ rowEnd) {
    __shared__ unsigned int stage[CAP];
    __shared__ int ncnt[512], nstart[512];
    const int b = blockIdx.x;
    const int t = threadIdx.x;
    const int cnt_b = min(bucketFill[b], CAP);
    ncnt[t] = 0;
    __syncthreads();
    for (int i = t; i < cnt_b; i += 512) {
        unsigned int e = binArr[(size_t)b * CAP + i];
        stage[i] = e;
        atomicAdd(&ncnt[e >> 17], 1);
    }
    __syncthreads();
    int v = ncnt[t];
    for (int off = 1; off < 512; off <<= 1) {
        int add = (t >= off) ? ncnt[t - off] : 0;
        __syncthreads();
        ncnt[t] += add;
        __syncthreads();
    }
    int start = ncnt[t] - v;
    nstart[t] = start;
    int n = (b << 9) + t;
    if (n < NNODES) {
        rowBeg[n] = b * CAP + start;
        rowEnd[n] = b * CAP + start + v;
    }
    __syncthreads();
    for (int i = t; i < cnt_b; i += 512) {
        unsigned int e = stage[i];
        int p = atomicAdd(&nstart[e >> 17], 1);
        sortedSrc[(size_t)b * CAP + p] = e & 0x1FFFFu;
    }
}

// ---------------- fused aggregate + SAGE GEMM ----------------
// Block = 64 nodes. Phase A: each wave aggregates 16 nodes (pk-i16 max on
// encoded rows, 4 gathers in flight, pipelined next-node prefetch) into LDS As.
// Phase B: MFMA. half0 A = As (aggregates); half1 A = As restaged with decoded
// root rows (coalesced). Weights staged in BK=64 chunks (Bs 68-stride).
template<int BN, bool RELU, bool ENCOUT, typename OutT>
__global__ __launch_bounds__(256, 4) void sage_fused(
        const uint4* __restrict__ xe4,             // [M][16] encoded bf16
        const int* __restrict__ rowBeg,
        const int* __restrict__ rowEnd,
        const unsigned int* __restrict__ sortedSrc,
        const unsigned short* __restrict__ Wtl,    // [BN][KP] bf16
        const unsigned short* __restrict__ Wtr,    // [BN][KP] bf16
        const float* __restrict__ bias,            // [BN] f32
        OutT* __restrict__ C,                      // [M][BN]
        int M) {
    constexpr int NT = BN / 16;
    __shared__ __align__(16) unsigned short As[64 * KP];    // 17.4 KB
    __shared__ __align__(16) unsigned short Bs[BN * 68];    // BN*136 B

    const int tid = threadIdx.x;
    const int w = tid >> 6;
    const int lane = tid & 63;
    const int grp = lane >> 4;
    const int c16 = lane & 15;
    const int mrow = lane & 15;
    const int quad = lane >> 4;
    const int base0 = blockIdx.x * 64;

    // ---- phase A: aggregate 16 nodes per wave into As (plain bf16) ----
    int bl = 0, el = 0;
    {
        int nn = base0 + w * 16 + (lane & 15);
        if (nn < M) { bl = rowBeg[nn]; el = rowEnd[nn]; }
    }
    int nbeg = __shfl(bl, 0), nend = __shfl(el, 0);
    int nid = (nend > nbeg) ? (int)sortedSrc[min(nbeg + lane, nend - 1)] : 0;
    for (int i = 0; i < 16; ++i) {
        const int beg = nbeg, end = nend;
        const int myid = nid;
        if (i < 15) {   // prefetch next node's batch while this one reduces
            nbeg = __shfl(bl, i + 1);
            nend = __shfl(el, i + 1);
            nid = (nend > nbeg) ? (int)sortedSrc[min(nbeg + lane, nend - 1)] : 0;
        }
        const int r = w * 16 + i;
        if (end <= beg) {                     // isolated / OOB node -> zero row
            if (lane < 16) {
                uint4 z; z.x = z.y = z.z = z.w = 0u;
                ((uint4*)As)[r * 17 + c16] = z;
            }
            continue;
        }
        unsigned a0 = 0x80008000u, a1 = 0x80008000u, a2 = 0x80008000u, a3 = 0x80008000u;
        {
            const int m = min(end - beg, 64);
            for (int j = 0; j < m; j += 16) {     // 4 independent 4-row gathers
                int s0 = __shfl(myid, j + grp);
                int s1 = __shfl(myid, j + 4 + grp);
                int s2 = __shfl(myid, j + 8 + grp);
                int s3 = __shfl(myid, j + 12 + grp);
                uint4 p0 = xe4[(size_t)s0 * 16 + c16];
                uint4 p1 = xe4[(size_t)s1 * 16 + c16];
                uint4 p2 = xe4[(size_t)s2 * 16 + c16];
                uint4 p3 = xe4[(size_t)s3 * 16 + c16];
                a0 = pkmax(a0, pkmax(pkmax(p0.x, p1.x), pkmax(p2.x, p3.x)));
                a1 = pkmax(a1, pkmax(pkmax(p0.y, p1.y), pkmax(p2.y, p3.y)));
                a2 = pkmax(a2, pkmax(pkmax(p0.z, p1.z), pkmax(p2.z, p3.z)));
                a3 = pkmax(a3, pkmax(pkmax(p0.w, p1.w), pkmax(p2.w, p3.w)));
            }
        }
        for (int bs = beg + 64; bs < end; bs += 64) {   // rare: degree > 64
            int bid = (int)sortedSrc[min(bs + lane, end - 1)];
            const int m = min(end - bs, 64);
            for (int j = 0; j < m; j += 16) {
                int s0 = __shfl(bid, j + grp);
                int s1 = __shfl(bid, j + 4 + grp);
                int s2 = __shfl(bid, j + 8 + grp);
                int s3 = __shfl(bid, j + 12 + grp);
                uint4 p0 = xe4[(size_t)s0 * 16 + c16];
                uint4 p1 = xe4[(size_t)s1 * 16 + c16];
                uint4 p2 = xe4[(size_t)s2 * 16 + c16];
                uint4 p3 = xe4[(size_t)s3 * 16 + c16];
                a0 = pkmax(a0, pkmax(pkmax(p0.x, p1.x), pkmax(p2.x, p3.x)));
                a1 = pkmax(a1, pkmax(pkmax(p0.y, p1.y), pkmax(p2.y, p3.y)));
                a2 = pkmax(a2, pkmax(pkmax(p0.z, p1.z), pkmax(p2.z, p3.z)));
                a3 = pkmax(a3, pkmax(pkmax(p0.w, p1.w), pkmax(p2.w, p3.w)));
            }
        }
        // merge the 4 edge-groups (lane bits 4,5), decode, store row to LDS
        a0 = pkmax(a0, (unsigned)__shfl_xor((int)a0, 16));
        a1 = pkmax(a1, (unsigned)__shfl_xor((int)a1, 16));
        a2 = pkmax(a2, (unsigned)__shfl_xor((int)a2, 16));
        a3 = pkmax(a3, (unsigned)__shfl_xor((int)a3, 16));
        a0 = pkmax(a0, (unsigned)__shfl_xor((int)a0, 32));
        a1 = pkmax(a1, (unsigned)__shfl_xor((int)a1, 32));
        a2 = pkmax(a2, (unsigned)__shfl_xor((int)a2, 32));
        a3 = pkmax(a3, (unsigned)__shfl_xor((int)a3, 32));
        if (lane < 16) {
            uint4 o;
            o.x = encdec(a0); o.y = encdec(a1); o.z = encdec(a2); o.w = encdec(a3);
            ((uint4*)As)[r * 17 + c16] = o;
        }
    }

    // ---- phase B: MFMA ----
    f32x4 acc[NT];
#pragma unroll
    for (int nt = 0; nt < NT; ++nt) acc[nt] = (f32x4){0.f, 0.f, 0.f, 0.f};
    __syncthreads();

    for (int half = 0; half < 2; ++half) {
        if (half == 1) {
            __syncthreads();   // all agg-half MFMA reads of As done
            // restage As with decoded root rows (coalesced global reads)
            const uint2* xs = (const uint2*)xe4;
            for (int i2 = tid; i2 < 64 * 32; i2 += 256) {
                int r = i2 >> 5, c = i2 & 31;
                int gr = base0 + r;
                if (gr >= M) gr = 0;          // junk row; stores guarded later
                uint2 vv = xs[(size_t)gr * 32 + c];
                vv.x = encdec(vv.x); vv.y = encdec(vv.y);
                ((uint2*)As)[r * 34 + c] = vv;
            }
        }
        const unsigned short* Wt = half ? Wtr : Wtl;
        for (int ks = 0; ks < 2; ++ks) {
            __syncthreads();   // protect Bs (and As restage on half1/ks0)
            const uint2* wsrc = (const uint2*)Wt;
            for (int i2 = tid; i2 < BN * 16; i2 += 256) {
                int n = i2 >> 4, c = i2 & 15;
                ((uint2*)Bs)[n * 17 + c] = wsrc[n * 34 + ks * 16 + c];
            }
            __syncthreads();
#pragma unroll
            for (int kt2 = 0; kt2 < 2; ++kt2) {
                bf16x8 a = *(const bf16x8*)(As + (w * 16 + mrow) * KP +
                                            ks * 64 + kt2 * 32 + quad * 8);
#pragma unroll
                for (int nt = 0; nt < NT; ++nt) {
                    bf16x8 b = *(const bf16x8*)(Bs + (nt * 16 + mrow) * 68 +
                                                kt2 * 32 + quad * 8);
                    acc[nt] = __builtin_amdgcn_mfma_f32_16x16x32_bf16(a, b, acc[nt], 0, 0, 0);
                }
            }
        }
    }

    // ---- epilogue: D layout col=lane&15, row=quad*4+reg ----
    const int rowD = base0 + w * 16 + quad * 4;
#pragma unroll
    for (int nt = 0; nt < NT; ++nt) {
        int col = nt * 16 + mrow;
        float bv = bias[col];
#pragma unroll
        for (int r = 0; r < 4; ++r) {
            int grow = rowD + r;
            if (grow < M) {
                float v = acc[nt][r] + bv;
                if (RELU) v = fmaxf(v, 0.0f);
                if constexpr (ENCOUT) {
                    unsigned u = f2bf_rne(v);
                    u ^= ((u >> 15) & 1u) * 0x7FFFu;   // encode for next layer
                    C[(size_t)grow * BN + col] = (OutT)u;
                } else {
                    C[(size_t)grow * BN + col] = (OutT)v;
                }
            }
        }
    }
}

extern "C" void kernel_launch(void* const* d_in, const int* in_sizes, int n_in,
                              void* d_out, int out_size, void* d_ws, size_t ws_size,
                              hipStream_t stream) {
    const float* x   = (const float*)d_in[0];
    const int*   ei  = (const int*)d_in[1];
    const float* W1l = (const float*)d_in[2];
    const float* b1l = (const float*)d_in[3];
    const float* W1r = (const float*)d_in[4];
    const float* W2l = (const float*)d_in[5];
    const float* b2l = (const float*)d_in[6];
    const float* W2r = (const float*)d_in[7];
    float* out = (float*)d_out;

    const int* src = ei;
    const int* dst = ei + NEDGES;

    // ---- workspace layout ----
    char* ws = (char*)d_ws;
    unsigned short* xe = (unsigned short*)ws; ws += (size_t)NNODES * 128 * 2;  // 25.6 MB (encoded)
    unsigned short* he = (unsigned short*)ws; ws += (size_t)NNODES * 128 * 2;  // 25.6 MB (encoded)
    unsigned int* binArr    = (unsigned int*)ws; ws += (size_t)NBKT * CAP * 4; // 7.2 MB
    unsigned int* sortedSrc = (unsigned int*)ws; ws += (size_t)NBKT * CAP * 4; // 7.2 MB
    int* rowBeg     = (int*)ws; ws += (size_t)NNODES * 4;
    int* rowEnd     = (int*)ws; ws += (size_t)NNODES * 4;
    int* bucketFill = (int*)ws; ws += 256 * 4;
    unsigned short* T1l = (unsigned short*)ws; ws += 128 * KP * 2;
    unsigned short* T1r = (unsigned short*)ws; ws += 128 * KP * 2;
    unsigned short* T2l = (unsigned short*)ws; ws += 64 * KP * 2;
    unsigned short* T2r = (unsigned short*)ws; ws += 64 * KP * 2;

    const int gGemm = (NNODES + 63) / 64;   // 1563

    prep1_kernel<<<65, 256, 0, stream>>>(W1l, W1r, W2l, W2r, T1l, T1r, T2l, T2r, bucketFill);
    prep2_kernel<<<GBIN + GCVT, 256, 0, stream>>>(src, dst, binArr, bucketFill,
                                                  (const float4*)x, (uint4*)xe, NEDGES);
    build_csr_kernel<<<NBKT, 512, 0, stream>>>(binArr, bucketFill, sortedSrc, rowBeg, rowEnd);

    sage_fused<128, true, true, unsigned short><<<gGemm, 256, 0, stream>>>(
        (const uint4*)xe, rowBeg, rowEnd, sortedSrc, T1l, T1r, b1l, he, NNODES);
    sage_fused<64, false, false, float><<<gGemm, 256, 0, stream>>>(
        (const uint4*)he, rowBeg, rowEnd, sortedSrc, T2l, T2r, b2l, out, NNODES);
}

// Round 8
// 297.921 us; speedup vs baseline: 21.5331x; 1.0210x over previous
//
#include <hip/hip_runtime.h>
#include <cstdint>

#define NNODES 100000
#define NEDGES 1600000
#define NBKT   196          // ceil(NNODES / 512); bucket = dst >> 9
#define CAP    9216         // per-bucket capacity: mean 8192 + ~11 sigma
#define BIN_CHUNK 4096
#define GBIN ((NEDGES + BIN_CHUNK - 1) / BIN_CHUNK)   // 391
#define GCVT (NNODES * 128 / 8 / 256)                 // 6250 (8 floats/thread)

typedef __attribute__((ext_vector_type(8))) __bf16 bf16x8;
typedef __attribute__((ext_vector_type(4))) float f32x4;
typedef short v2s __attribute__((ext_vector_type(2)));

__device__ __forceinline__ unsigned short f2bf_rne(float f) {
    unsigned int u = __float_as_uint(f);
    u += 0x7fffu + ((u >> 16) & 1u);
    return (unsigned short)(u >> 16);
}
// involutive monotone map: bf16 float order <-> signed i16 order (per packed half)
__device__ __forceinline__ unsigned encdec(unsigned u) {
    return u ^ (((u & 0x80008000u) >> 15) * 0x7FFFu);
}
__device__ __forceinline__ unsigned pkmax(unsigned a, unsigned b) {
    v2s r = __builtin_elementwise_max(__builtin_bit_cast(v2s, a), __builtin_bit_cast(v2s, b));
    return __builtin_bit_cast(unsigned, r);
}

// ---------------- prep1: zero bucketFill + pack weights into MFMA B-fragment
// layout: Wf[slot = ((h*4+kt)*NT + nt)*64 + lane] = 8 bf16 (uint4), where lane
// (mrow=lane&15, quad=lane>>4) holds W_h[kt*32+quad*8+j][nt*16+mrow], j=0..7.
__global__ __launch_bounds__(256) void prep1_kernel(
        const float* __restrict__ W1l, const float* __restrict__ W1r,
        const float* __restrict__ W2l, const float* __restrict__ W2r,
        uint4* __restrict__ Wf1, uint4* __restrict__ Wf2,
        int* __restrict__ bucketFill) {
    if (blockIdx.x == 24) { bucketFill[threadIdx.x] = 0; return; }
    int t = blockIdx.x * 256 + threadIdx.x;   // 0..6143
    unsigned short s[8];
    if (t < 4096) {                           // layer 1: BN=128, NT=8
        int h = t >> 11, kt = (t >> 9) & 3, nt = (t >> 6) & 7, lane = t & 63;
        const float* W = h ? W1r : W1l;
        int k0 = kt * 32 + (lane >> 4) * 8;
        int col = nt * 16 + (lane & 15);
#pragma unroll
        for (int j = 0; j < 8; ++j) s[j] = f2bf_rne(W[(k0 + j) * 128 + col]);
        uint4 o;
        o.x = (unsigned)s[0] | ((unsigned)s[1] << 16);
        o.y = (unsigned)s[2] | ((unsigned)s[3] << 16);
        o.z = (unsigned)s[4] | ((unsigned)s[5] << 16);
        o.w = (unsigned)s[6] | ((unsigned)s[7] << 16);
        Wf1[t] = o;
    } else {                                  // layer 2: BN=64, NT=4
        int u = t - 4096;                     // 0..2047
        int h = u >> 10, kt = (u >> 8) & 3, nt = (u >> 6) & 3, lane = u & 63;
        const float* W = h ? W2r : W2l;
        int k0 = kt * 32 + (lane >> 4) * 8;
        int col = nt * 16 + (lane & 15);
#pragma unroll
        for (int j = 0; j < 8; ++j) s[j] = f2bf_rne(W[(k0 + j) * 64 + col]);
        uint4 o;
        o.x = (unsigned)s[0] | ((unsigned)s[1] << 16);
        o.y = (unsigned)s[2] | ((unsigned)s[3] << 16);
        o.z = (unsigned)s[4] | ((unsigned)s[5] << 16);
        o.w = (unsigned)s[6] | ((unsigned)s[7] << 16);
        Wf2[u] = o;
    }
}

// ---------------- prep2: bin edges (blocks [0,GBIN)) + encode x (rest) --------
__global__ __launch_bounds__(256) void prep2_kernel(
        const int* __restrict__ src, const int* __restrict__ dst,
        unsigned int* __restrict__ binArr, int* __restrict__ bucketFill,
        const float4* __restrict__ xin, uint4* __restrict__ xeout, int nE) {
    if (blockIdx.x >= GBIN) {
        int i = (blockIdx.x - GBIN) * 256 + threadIdx.x;  // < 1.6M
        float4 v0 = xin[(size_t)2 * i], v1 = xin[(size_t)2 * i + 1];
        uint4 o;
        o.x = encdec((unsigned)f2bf_rne(v0.x) | ((unsigned)f2bf_rne(v0.y) << 16));
        o.y = encdec((unsigned)f2bf_rne(v0.z) | ((unsigned)f2bf_rne(v0.w) << 16));
        o.z = encdec((unsigned)f2bf_rne(v1.x) | ((unsigned)f2bf_rne(v1.y) << 16));
        o.w = encdec((unsigned)f2bf_rne(v1.z) | ((unsigned)f2bf_rne(v1.w) << 16));
        xeout[i] = o;
        return;
    }
    // ---- bin: entry = (dst&511)<<17 | src ----
    __shared__ unsigned int stage[BIN_CHUNK];
    __shared__ unsigned char bof[BIN_CHUNK];
    __shared__ int cnt[256], cstart[256], cfill[256], gbase[256];
    const int tid = threadIdx.x;
    const int blockStart = blockIdx.x * BIN_CHUNK;
    const int chunkN = min(BIN_CHUNK, nE - blockStart);
    cnt[tid] = 0;
    __syncthreads();
    int myd[16], mys[16];
#pragma unroll
    for (int i = 0; i < 16; ++i) {
        int idx = i * 256 + tid;
        if (idx < chunkN) {
            myd[i] = dst[blockStart + idx];
            mys[i] = src[blockStart + idx];
            atomicAdd(&cnt[myd[i] >> 9], 1);
        }
    }
    __syncthreads();
    int v = cnt[tid];
    for (int off = 1; off < 256; off <<= 1) {
        int add = (tid >= off) ? cnt[tid - off] : 0;
        __syncthreads();
        cnt[tid] += add;
        __syncthreads();
    }
    cstart[tid] = cnt[tid] - v;
    cfill[tid] = cnt[tid] - v;
    if (tid < NBKT && v > 0) gbase[tid] = atomicAdd(&bucketFill[tid], v);
    __syncthreads();
#pragma unroll
    for (int i = 0; i < 16; ++i) {
        int idx = i * 256 + tid;
        if (idx < chunkN) {
            int b = myd[i] >> 9;
            int p = atomicAdd(&cfill[b], 1);
            stage[p] = ((unsigned)(myd[i] & 511) << 17) | (unsigned)mys[i];
            bof[p] = (unsigned char)b;
        }
    }
    __syncthreads();
#pragma unroll
    for (int i = 0; i < 16; ++i) {
        int idx = i * 256 + tid;
        if (idx < chunkN) {
            int b = bof[idx];
            int slot = gbase[b] + (idx - cstart[b]);
            if (slot < CAP) binArr[(size_t)b * CAP + slot] = stage[idx];
        }
    }
}

// ---------------- per-bucket CSR build, all in LDS ----------------
__global__ __launch_bounds__(512) void build_csr_kernel(
        const unsigned int* __restrict__ binArr, const int* __restrict__ bucketFill,
        unsigned int* __restrict__ sortedSrc,
        int* __restrict__ rowBeg, int* __restrict__ rowEnd) {
    __shared__ unsigned int stage[CAP];
    __shared__ int ncnt[512], nstart[512];
    const int b = blockIdx.x;
    const int t = threadIdx.x;
    const int cnt_b = min(bucketFill[b], CAP);
    ncnt[t] = 0;
    __syncthreads();
    for (int i = t; i < cnt_b; i += 512) {
        unsigned int e = binArr[(size_t)b * CAP + i];
        stage[i] = e;
        atomicAdd(&ncnt[e >> 17], 1);
    }
    __syncthreads();
    int v = ncnt[t];
    for (int off = 1; off < 512; off <<= 1) {
        int add = (t >= off) ? ncnt[t - off] : 0;
        __syncthreads();
        ncnt[t] += add;
        __syncthreads();
    }
    int start = ncnt[t] - v;
    nstart[t] = start;
    int n = (b << 9) + t;
    if (n < NNODES) {
        rowBeg[n] = b * CAP + start;
        rowEnd[n] = b * CAP + start + v;
    }
    __syncthreads();
    for (int i = t; i < cnt_b; i += 512) {
        unsigned int e = stage[i];
        int p = atomicAdd(&nstart[e >> 17], 1);
        sortedSrc[(size_t)b * CAP + p] = e & 0x1FFFFu;
    }
}

// ---------------- fused aggregate + SAGE GEMM, barrier-free ----------------
// Block = 64 nodes, 4 waves; wave w owns rows w*16..w*16+15 end-to-end:
// phase A aggregates them into its private As quarter, phase B MFMAs from it.
// NO __syncthreads anywhere. B-operands from pre-packed global fragments
// (L1/L2-resident); root A-operand gathered directly from xe (L2-hot).
template<int BN, bool RELU, bool ENCOUT, typename OutT>
__global__ __launch_bounds__(256, 6) void sage_fused(
        const uint4* __restrict__ xe4,             // [M][16] encoded bf16
        const int* __restrict__ rowBeg,
        const int* __restrict__ rowEnd,
        const unsigned int* __restrict__ sortedSrc,
        const uint4* __restrict__ Wf,              // fragment-packed weights
        const float* __restrict__ bias,            // [BN] f32
        OutT* __restrict__ C,                      // [M][BN]
        int M) {
    constexpr int NT = BN / 16;
    __shared__ __align__(16) unsigned short As[64 * 136];   // 17.4 KB (wave-private quarters)

    const int tid = threadIdx.x;
    const int w = tid >> 6;
    const int lane = tid & 63;
    const int grp = lane >> 4;    // edge-group in phase A; quad in phase B
    const int c16 = lane & 15;    // 16B-chunk in phase A; mrow in phase B
    const int base0 = blockIdx.x * 64;

    // ---- phase A: aggregate 16 nodes into As (encoded pk-i16 max -> decode) ----
    int bl = 0, el = 0;
    {
        int nn = base0 + w * 16 + c16;
        if (nn < M) { bl = rowBeg[nn]; el = rowEnd[nn]; }
    }
    int nbeg = __shfl(bl, 0), nend = __shfl(el, 0);
    int nid = (nend > nbeg) ? (int)sortedSrc[min(nbeg + lane, nend - 1)] : 0;
    for (int i = 0; i < 16; ++i) {
        const int beg = nbeg, end = nend;
        const int myid = nid;
        if (i < 15) {   // prefetch next node's batch while this one reduces
            nbeg = __shfl(bl, i + 1);
            nend = __shfl(el, i + 1);
            nid = (nend > nbeg) ? (int)sortedSrc[min(nbeg + lane, nend - 1)] : 0;
        }
        const int r = w * 16 + i;
        if (end <= beg) {                     // isolated / OOB node -> zero row
            if (lane < 16) {
                uint4 z; z.x = z.y = z.z = z.w = 0u;
                ((uint4*)As)[r * 17 + c16] = z;
            }
            continue;
        }
        unsigned a0 = 0x80008000u, a1 = 0x80008000u, a2 = 0x80008000u, a3 = 0x80008000u;
        {
            const int m = min(end - beg, 64);
            for (int j = 0; j < m; j += 16) {     // 4 independent row gathers
                int s0 = __shfl(myid, j + grp);
                int s1 = __shfl(myid, j + 4 + grp);
                int s2 = __shfl(myid, j + 8 + grp);
                int s3 = __shfl(myid, j + 12 + grp);
                uint4 p0 = xe4[(size_t)s0 * 16 + c16];
                uint4 p1 = xe4[(size_t)s1 * 16 + c16];
                uint4 p2 = xe4[(size_t)s2 * 16 + c16];
                uint4 p3 = xe4[(size_t)s3 * 16 + c16];
                a0 = pkmax(a0, pkmax(pkmax(p0.x, p1.x), pkmax(p2.x, p3.x)));
                a1 = pkmax(a1, pkmax(pkmax(p0.y, p1.y), pkmax(p2.y, p3.y)));
                a2 = pkmax(a2, pkmax(pkmax(p0.z, p1.z), pkmax(p2.z, p3.z)));
                a3 = pkmax(a3, pkmax(pkmax(p0.w, p1.w), pkmax(p2.w, p3.w)));
            }
        }
        for (int bs = beg + 64; bs < end; bs += 64) {   // rare: degree > 64
            int bid = (int)sortedSrc[min(bs + lane, end - 1)];
            const int m = min(end - bs, 64);
            for (int j = 0; j < m; j += 16) {
                int s0 = __shfl(bid, j + grp);
                int s1 = __shfl(bid, j + 4 + grp);
                int s2 = __shfl(bid, j + 8 + grp);
                int s3 = __shfl(bid, j + 12 + grp);
                uint4 p0 = xe4[(size_t)s0 * 16 + c16];
                uint4 p1 = xe4[(size_t)s1 * 16 + c16];
                uint4 p2 = xe4[(size_t)s2 * 16 + c16];
                uint4 p3 = xe4[(size_t)s3 * 16 + c16];
                a0 = pkmax(a0, pkmax(pkmax(p0.x, p1.x), pkmax(p2.x, p3.x)));
                a1 = pkmax(a1, pkmax(pkmax(p0.y, p1.y), pkmax(p2.y, p3.y)));
                a2 = pkmax(a2, pkmax(pkmax(p0.z, p1.z), pkmax(p2.z, p3.z)));
                a3 = pkmax(a3, pkmax(pkmax(p0.w, p1.w), pkmax(p2.w, p3.w)));
            }
        }
        // merge the 4 edge-groups (lane bits 4,5), decode, store row to LDS
        a0 = pkmax(a0, (unsigned)__shfl_xor((int)a0, 16));
        a1 = pkmax(a1, (unsigned)__shfl_xor((int)a1, 16));
        a2 = pkmax(a2, (unsigned)__shfl_xor((int)a2, 16));
        a3 = pkmax(a3, (unsigned)__shfl_xor((int)a3, 16));
        a0 = pkmax(a0, (unsigned)__shfl_xor((int)a0, 32));
        a1 = pkmax(a1, (unsigned)__shfl_xor((int)a1, 32));
        a2 = pkmax(a2, (unsigned)__shfl_xor((int)a2, 32));
        a3 = pkmax(a3, (unsigned)__shfl_xor((int)a3, 32));
        if (lane < 16) {
            uint4 o;
            o.x = encdec(a0); o.y = encdec(a1); o.z = encdec(a2); o.w = encdec(a3);
            ((uint4*)As)[r * 17 + c16] = o;
        }
    }

    // ---- phase B: MFMA straight out of the wave-private As quarter ----
    f32x4 acc[NT];
#pragma unroll
    for (int nt = 0; nt < NT; ++nt) acc[nt] = (f32x4){0.f, 0.f, 0.f, 0.f};

    const int rowR = base0 + w * 16 + c16;            // root row (mrow = c16)
    const int rowRc = (rowR < M) ? rowR : 0;
#pragma unroll
    for (int kt = 0; kt < 4; ++kt) {
        // agg A-fragment from LDS (stride 68 dwords === 4 mod 32: conflict-free)
        bf16x8 aa = *(const bf16x8*)(As + (w * 16 + c16) * 136 + kt * 32 + grp * 8);
        // root A-fragment direct from global (L2-hot), decode in-flight
        uint4 tr = xe4[(size_t)rowRc * 16 + kt * 4 + grp];
        tr.x = encdec(tr.x); tr.y = encdec(tr.y); tr.z = encdec(tr.z); tr.w = encdec(tr.w);
        bf16x8 ar = __builtin_bit_cast(bf16x8, tr);
#pragma unroll
        for (int nt = 0; nt < NT; ++nt) {
            bf16x8 b0 = __builtin_bit_cast(bf16x8, Wf[(kt * NT + nt) * 64 + lane]);
            acc[nt] = __builtin_amdgcn_mfma_f32_16x16x32_bf16(aa, b0, acc[nt], 0, 0, 0);
            bf16x8 b1 = __builtin_bit_cast(bf16x8, Wf[((4 + kt) * NT + nt) * 64 + lane]);
            acc[nt] = __builtin_amdgcn_mfma_f32_16x16x32_bf16(ar, b1, acc[nt], 0, 0, 0);
        }
    }

    // ---- epilogue: D layout col=lane&15, row=quad*4+reg ----
    const int rowD = base0 + w * 16 + grp * 4;
#pragma unroll
    for (int nt = 0; nt < NT; ++nt) {
        int col = nt * 16 + c16;
        float bv = bias[col];
#pragma unroll
        for (int r = 0; r < 4; ++r) {
            int grow = rowD + r;
            if (grow < M) {
                float v = acc[nt][r] + bv;
                if (RELU) v = fmaxf(v, 0.0f);
                if constexpr (ENCOUT) {
                    unsigned u = f2bf_rne(v);
                    u ^= ((u >> 15) & 1u) * 0x7FFFu;   // encode for next layer
                    C[(size_t)grow * BN + col] = (OutT)u;
                } else {
                    C[(size_t)grow * BN + col] = (OutT)v;
                }
            }
        }
    }
}

extern "C" void kernel_launch(void* const* d_in, const int* in_sizes, int n_in,
                              void* d_out, int out_size, void* d_ws, size_t ws_size,
                              hipStream_t stream) {
    const float* x   = (const float*)d_in[0];
    const int*   ei  = (const int*)d_in[1];
    const float* W1l = (const float*)d_in[2];
    const float* b1l = (const float*)d_in[3];
    const float* W1r = (const float*)d_in[4];
    const float* W2l = (const float*)d_in[5];
    const float* b2l = (const float*)d_in[6];
    const float* W2r = (const float*)d_in[7];
    float* out = (float*)d_out;

    const int* src = ei;
    const int* dst = ei + NEDGES;

    // ---- workspace layout ----
    char* ws = (char*)d_ws;
    unsigned short* xe = (unsigned short*)ws; ws += (size_t)NNODES * 128 * 2;  // 25.6 MB (encoded)
    unsigned short* he = (unsigned short*)ws; ws += (size_t)NNODES * 128 * 2;  // 25.6 MB (encoded)
    unsigned int* binArr    = (unsigned int*)ws; ws += (size_t)NBKT * CAP * 4; // 7.2 MB
    unsigned int* sortedSrc = (unsigned int*)ws; ws += (size_t)NBKT * CAP * 4; // 7.2 MB
    int* rowBeg     = (int*)ws; ws += (size_t)NNODES * 4;
    int* rowEnd     = (int*)ws; ws += (size_t)NNODES * 4;
    int* bucketFill = (int*)ws; ws += 256 * 4;
    uint4* Wf1 = (uint4*)ws; ws += 4096 * 16;   // 64 KB fragment-packed L1 weights
    uint4* Wf2 = (uint4*)ws; ws += 2048 * 16;   // 32 KB fragment-packed L2 weights

    const int gGemm = (NNODES + 63) / 64;   // 1563

    prep1_kernel<<<25, 256, 0, stream>>>(W1l, W1r, W2l, W2r, Wf1, Wf2, bucketFill);
    prep2_kernel<<<GBIN + GCVT, 256, 0, stream>>>(src, dst, binArr, bucketFill,
                                                  (const float4*)x, (uint4*)xe, NEDGES);
    build_csr_kernel<<<NBKT, 512, 0, stream>>>(binArr, bucketFill, sortedSrc, rowBeg, rowEnd);

    sage_fused<128, true, true, unsigned short><<<gGemm, 256, 0, stream>>>(
        (const uint4*)xe, rowBeg, rowEnd, sortedSrc, Wf1, b1l, he, NNODES);
    sage_fused<64, false, false, float><<<gGemm, 256, 0, stream>>>(
        (const uint4*)he, rowBeg, rowEnd, sortedSrc, Wf2, b2l, out, NNODES);
}

// Round 9
// 294.192 us; speedup vs baseline: 21.8060x; 1.0127x over previous
//
#include <hip/hip_runtime.h>
#include <cstdint>

#define NNODES 100000
#define NEDGES 1600000
#define NBKT   196          // ceil(NNODES / 512); bucket = dst >> 9
#define CAP    9216         // per-bucket capacity: mean 8192 + ~11 sigma
#define BIN_CHUNK 4096
#define GBIN ((NEDGES + BIN_CHUNK - 1) / BIN_CHUNK)   // 391
#define GCVT (NNODES * 128 / 8 / 256)                 // 6250 (8 floats/thread)

typedef __attribute__((ext_vector_type(8))) __bf16 bf16x8;
typedef __attribute__((ext_vector_type(4))) float f32x4;
typedef short v2s __attribute__((ext_vector_type(2)));

__device__ __forceinline__ unsigned short f2bf_rne(float f) {
    unsigned int u = __float_as_uint(f);
    u += 0x7fffu + ((u >> 16) & 1u);
    return (unsigned short)(u >> 16);
}
// involutive monotone map: bf16 float order <-> signed i16 order (per packed half)
__device__ __forceinline__ unsigned encdec(unsigned u) {
    return u ^ (((u & 0x80008000u) >> 15) * 0x7FFFu);
}
__device__ __forceinline__ unsigned pkmax(unsigned a, unsigned b) {
    v2s r = __builtin_elementwise_max(__builtin_bit_cast(v2s, a), __builtin_bit_cast(v2s, b));
    return __builtin_bit_cast(unsigned, r);
}

// ---------------- prep1: zero bucketFill + pack weights into MFMA B-fragment
// layout: Wf[slot = ((h*4+kt)*NT + nt)*64 + lane] = 8 bf16 (uint4), where lane
// (mrow=lane&15, quad=lane>>4) holds W_h[kt*32+quad*8+j][nt*16+mrow], j=0..7.
__global__ __launch_bounds__(256) void prep1_kernel(
        const float* __restrict__ W1l, const float* __restrict__ W1r,
        const float* __restrict__ W2l, const float* __restrict__ W2r,
        uint4* __restrict__ Wf1, uint4* __restrict__ Wf2,
        int* __restrict__ bucketFill) {
    if (blockIdx.x == 24) { bucketFill[threadIdx.x] = 0; return; }
    int t = blockIdx.x * 256 + threadIdx.x;   // 0..6143
    unsigned short s[8];
    if (t < 4096) {                           // layer 1: BN=128, NT=8
        int h = t >> 11, kt = (t >> 9) & 3, nt = (t >> 6) & 7, lane = t & 63;
        const float* W = h ? W1r : W1l;
        int k0 = kt * 32 + (lane >> 4) * 8;
        int col = nt * 16 + (lane & 15);
#pragma unroll
        for (int j = 0; j < 8; ++j) s[j] = f2bf_rne(W[(k0 + j) * 128 + col]);
        uint4 o;
        o.x = (unsigned)s[0] | ((unsigned)s[1] << 16);
        o.y = (unsigned)s[2] | ((unsigned)s[3] << 16);
        o.z = (unsigned)s[4] | ((unsigned)s[5] << 16);
        o.w = (unsigned)s[6] | ((unsigned)s[7] << 16);
        Wf1[t] = o;
    } else {                                  // layer 2: BN=64, NT=4
        int u = t - 4096;                     // 0..2047
        int h = u >> 10, kt = (u >> 8) & 3, nt = (u >> 6) & 3, lane = u & 63;
        const float* W = h ? W2r : W2l;
        int k0 = kt * 32 + (lane >> 4) * 8;
        int col = nt * 16 + (lane & 15);
#pragma unroll
        for (int j = 0; j < 8; ++j) s[j] = f2bf_rne(W[(k0 + j) * 64 + col]);
        uint4 o;
        o.x = (unsigned)s[0] | ((unsigned)s[1] << 16);
        o.y = (unsigned)s[2] | ((unsigned)s[3] << 16);
        o.z = (unsigned)s[4] | ((unsigned)s[5] << 16);
        o.w = (unsigned)s[6] | ((unsigned)s[7] << 16);
        Wf2[u] = o;
    }
}

// ---------------- prep2: bin edges (blocks [0,GBIN)) + encode x (rest) --------
__global__ __launch_bounds__(256) void prep2_kernel(
        const int* __restrict__ src, const int* __restrict__ dst,
        unsigned int* __restrict__ binArr, int* __restrict__ bucketFill,
        const float4* __restrict__ xin, uint4* __restrict__ xeout, int nE) {
    if (blockIdx.x >= GBIN) {
        int i = (blockIdx.x - GBIN) * 256 + threadIdx.x;  // < 1.6M
        float4 v0 = xin[(size_t)2 * i], v1 = xin[(size_t)2 * i + 1];
        uint4 o;
        o.x = encdec((unsigned)f2bf_rne(v0.x) | ((unsigned)f2bf_rne(v0.y) << 16));
        o.y = encdec((unsigned)f2bf_rne(v0.z) | ((unsigned)f2bf_rne(v0.w) << 16));
        o.z = encdec((unsigned)f2bf_rne(v1.x) | ((unsigned)f2bf_rne(v1.y) << 16));
        o.w = encdec((unsigned)f2bf_rne(v1.z) | ((unsigned)f2bf_rne(v1.w) << 16));
        xeout[i] = o;
        return;
    }
    // ---- bin: entry = (dst&511)<<17 | src ----
    __shared__ unsigned int stage[BIN_CHUNK];
    __shared__ unsigned char bof[BIN_CHUNK];
    __shared__ int cnt[256], cstart[256], cfill[256], gbase[256];
    const int tid = threadIdx.x;
    const int blockStart = blockIdx.x * BIN_CHUNK;
    const int chunkN = min(BIN_CHUNK, nE - blockStart);
    cnt[tid] = 0;
    __syncthreads();
    int myd[16], mys[16];
#pragma unroll
    for (int i = 0; i < 16; ++i) {
        int idx = i * 256 + tid;
        if (idx < chunkN) {
            myd[i] = dst[blockStart + idx];
            mys[i] = src[blockStart + idx];
            atomicAdd(&cnt[myd[i] >> 9], 1);
        }
    }
    __syncthreads();
    int v = cnt[tid];
    for (int off = 1; off < 256; off <<= 1) {
        int add = (tid >= off) ? cnt[tid - off] : 0;
        __syncthreads();
        cnt[tid] += add;
        __syncthreads();
    }
    cstart[tid] = cnt[tid] - v;
    cfill[tid] = cnt[tid] - v;
    if (tid < NBKT && v > 0) gbase[tid] = atomicAdd(&bucketFill[tid], v);
    __syncthreads();
#pragma unroll
    for (int i = 0; i < 16; ++i) {
        int idx = i * 256 + tid;
        if (idx < chunkN) {
            int b = myd[i] >> 9;
            int p = atomicAdd(&cfill[b], 1);
            stage[p] = ((unsigned)(myd[i] & 511) << 17) | (unsigned)mys[i];
            bof[p] = (unsigned char)b;
        }
    }
    __syncthreads();
#pragma unroll
    for (int i = 0; i < 16; ++i) {
        int idx = i * 256 + tid;
        if (idx < chunkN) {
            int b = bof[idx];
            int slot = gbase[b] + (idx - cstart[b]);
            if (slot < CAP) binArr[(size_t)b * CAP + slot] = stage[idx];
        }
    }
}

// ---------------- per-bucket CSR build, all in LDS ----------------
__global__ __launch_bounds__(512) void build_csr_kernel(
        const unsigned int* __restrict__ binArr, const int* __restrict__ bucketFill,
        unsigned int* __restrict__ sortedSrc,
        int* __restrict__ rowBeg, int* __restrict__ rowEnd) {
    __shared__ unsigned int stage[CAP];
    __shared__ int ncnt[512], nstart[512];
    const int b = blockIdx.x;
    const int t = threadIdx.x;
    const int cnt_b = min(bucketFill[b], CAP);
    ncnt[t] = 0;
    __syncthreads();
    for (int i = t; i < cnt_b; i += 512) {
        unsigned int e = binArr[(size_t)b * CAP + i];
        stage[i] = e;
        atomicAdd(&ncnt[e >> 17], 1);
    }
    __syncthreads();
    int v = ncnt[t];
    for (int off = 1; off < 512; off <<= 1) {
        int add = (t >= off) ? ncnt[t - off] : 0;
        __syncthreads();
        ncnt[t] += add;
        __syncthreads();
    }
    int start = ncnt[t] - v;
    nstart[t] = start;
    int n = (b << 9) + t;
    if (n < NNODES) {
        rowBeg[n] = b * CAP + start;
        rowEnd[n] = b * CAP + start + v;
    }
    __syncthreads();
    for (int i = t; i < cnt_b; i += 512) {
        unsigned int e = stage[i];
        int p = atomicAdd(&nstart[e >> 17], 1);
        sortedSrc[(size_t)b * CAP + p] = e & 0x1FFFFu;
    }
}

// ---------------- aggregation: 2 nodes per wave, 8 gathers in flight --------
// Output stays ENCODED (decode happens in the GEMM fragment load).
__global__ __launch_bounds__(256) void aggregate_pk2(
        const uint4* __restrict__ xe4,          // [M][16] encoded bf16
        const int* __restrict__ rowBeg,
        const int* __restrict__ rowEnd,
        const unsigned int* __restrict__ sortedSrc,
        uint4* __restrict__ aggrE,              // [M][16] encoded bf16
        int nN) {
    const int wv = threadIdx.x >> 6;
    const int lane = threadIdx.x & 63;
    const int grp = lane >> 4;
    const int nA = blockIdx.x * 8 + wv * 2;
    const int nB = nA + 1;
    if (nA >= nN) return;
    const int begA = rowBeg[nA], endA = rowEnd[nA];
    int begB = 0, endB = 0;
    if (nB < nN) { begB = rowBeg[nB]; endB = rowEnd[nB]; }
    const int mA = endA - begA, mB = endB - begB;

    int idA = (mA > 0) ? (int)sortedSrc[min(begA + lane, endA - 1)] : 0;
    int idB = (mB > 0) ? (int)sortedSrc[min(begB + lane, endB - 1)] : 0;

    unsigned aA0 = 0x80008000u, aA1 = 0x80008000u, aA2 = 0x80008000u, aA3 = 0x80008000u;
    unsigned aB0 = 0x80008000u, aB1 = 0x80008000u, aB2 = 0x80008000u, aB3 = 0x80008000u;

    const int cA = min(mA, 64), cB = min(mB, 64);
    const int mm = max(cA, cB);
    for (int j = 0; j < mm; j += 16) {
        const bool doA = j < cA, doB = j < cB;
        uint4 pA0, pA1, pA2, pA3, pB0, pB1, pB2, pB3;
        if (doA) {                               // 4 independent row gathers (A)
            int s0 = __shfl(idA, j + grp);
            int s1 = __shfl(idA, j + 4 + grp);
            int s2 = __shfl(idA, j + 8 + grp);
            int s3 = __shfl(idA, j + 12 + grp);
            pA0 = xe4[(size_t)s0 * 16 + (lane & 15)];
            pA1 = xe4[(size_t)s1 * 16 + (lane & 15)];
            pA2 = xe4[(size_t)s2 * 16 + (lane & 15)];
            pA3 = xe4[(size_t)s3 * 16 + (lane & 15)];
        }
        if (doB) {                               // 4 more in flight (B)
            int s0 = __shfl(idB, j + grp);
            int s1 = __shfl(idB, j + 4 + grp);
            int s2 = __shfl(idB, j + 8 + grp);
            int s3 = __shfl(idB, j + 12 + grp);
            pB0 = xe4[(size_t)s0 * 16 + (lane & 15)];
            pB1 = xe4[(size_t)s1 * 16 + (lane & 15)];
            pB2 = xe4[(size_t)s2 * 16 + (lane & 15)];
            pB3 = xe4[(size_t)s3 * 16 + (lane & 15)];
        }
        if (doA) {
            aA0 = pkmax(aA0, pkmax(pkmax(pA0.x, pA1.x), pkmax(pA2.x, pA3.x)));
            aA1 = pkmax(aA1, pkmax(pkmax(pA0.y, pA1.y), pkmax(pA2.y, pA3.y)));
            aA2 = pkmax(aA2, pkmax(pkmax(pA0.z, pA1.z), pkmax(pA2.z, pA3.z)));
            aA3 = pkmax(aA3, pkmax(pkmax(pA0.w, pA1.w), pkmax(pA2.w, pA3.w)));
        }
        if (doB) {
            aB0 = pkmax(aB0, pkmax(pkmax(pB0.x, pB1.x), pkmax(pB2.x, pB3.x)));
            aB1 = pkmax(aB1, pkmax(pkmax(pB0.y, pB1.y), pkmax(pB2.y, pB3.y)));
            aB2 = pkmax(aB2, pkmax(pkmax(pB0.z, pB1.z), pkmax(pB2.z, pB3.z)));
            aB3 = pkmax(aB3, pkmax(pkmax(pB0.w, pB1.w), pkmax(pB2.w, pB3.w)));
        }
    }
    // rare (Poisson(16)): degree > 64 tails, handled per node
    for (int bs = begA + 64; bs < endA; bs += 64) {
        int bid = (int)sortedSrc[min(bs + lane, endA - 1)];
        const int m = min(endA - bs, 64);
        for (int j = 0; j < m; j += 16) {
            int s0 = __shfl(bid, j + grp);
            int s1 = __shfl(bid, j + 4 + grp);
            int s2 = __shfl(bid, j + 8 + grp);
            int s3 = __shfl(bid, j + 12 + grp);
            uint4 p0 = xe4[(size_t)s0 * 16 + (lane & 15)];
            uint4 p1 = xe4[(size_t)s1 * 16 + (lane & 15)];
            uint4 p2 = xe4[(size_t)s2 * 16 + (lane & 15)];
            uint4 p3 = xe4[(size_t)s3 * 16 + (lane & 15)];
            aA0 = pkmax(aA0, pkmax(pkmax(p0.x, p1.x), pkmax(p2.x, p3.x)));
            aA1 = pkmax(aA1, pkmax(pkmax(p0.y, p1.y), pkmax(p2.y, p3.y)));
            aA2 = pkmax(aA2, pkmax(pkmax(p0.z, p1.z), pkmax(p2.z, p3.z)));
            aA3 = pkmax(aA3, pkmax(pkmax(p0.w, p1.w), pkmax(p2.w, p3.w)));
        }
    }
    for (int bs = begB + 64; bs < endB; bs += 64) {
        int bid = (int)sortedSrc[min(bs + lane, endB - 1)];
        const int m = min(endB - bs, 64);
        for (int j = 0; j < m; j += 16) {
            int s0 = __shfl(bid, j + grp);
            int s1 = __shfl(bid, j + 4 + grp);
            int s2 = __shfl(bid, j + 8 + grp);
            int s3 = __shfl(bid, j + 12 + grp);
            uint4 p0 = xe4[(size_t)s0 * 16 + (lane & 15)];
            uint4 p1 = xe4[(size_t)s1 * 16 + (lane & 15)];
            uint4 p2 = xe4[(size_t)s2 * 16 + (lane & 15)];
            uint4 p3 = xe4[(size_t)s3 * 16 + (lane & 15)];
            aB0 = pkmax(aB0, pkmax(pkmax(p0.x, p1.x), pkmax(p2.x, p3.x)));
            aB1 = pkmax(aB1, pkmax(pkmax(p0.y, p1.y), pkmax(p2.y, p3.y)));
            aB2 = pkmax(aB2, pkmax(pkmax(p0.z, p1.z), pkmax(p2.z, p3.z)));
            aB3 = pkmax(aB3, pkmax(pkmax(p0.w, p1.w), pkmax(p2.w, p3.w)));
        }
    }
    // merge the 4 edge-groups (lane bits 4,5) -> all lanes hold the result
    aA0 = pkmax(aA0, (unsigned)__shfl_xor((int)aA0, 16));
    aA1 = pkmax(aA1, (unsigned)__shfl_xor((int)aA1, 16));
    aA2 = pkmax(aA2, (unsigned)__shfl_xor((int)aA2, 16));
    aA3 = pkmax(aA3, (unsigned)__shfl_xor((int)aA3, 16));
    aB0 = pkmax(aB0, (unsigned)__shfl_xor((int)aB0, 16));
    aB1 = pkmax(aB1, (unsigned)__shfl_xor((int)aB1, 16));
    aB2 = pkmax(aB2, (unsigned)__shfl_xor((int)aB2, 16));
    aB3 = pkmax(aB3, (unsigned)__shfl_xor((int)aB3, 16));
    aA0 = pkmax(aA0, (unsigned)__shfl_xor((int)aA0, 32));
    aA1 = pkmax(aA1, (unsigned)__shfl_xor((int)aA1, 32));
    aA2 = pkmax(aA2, (unsigned)__shfl_xor((int)aA2, 32));
    aA3 = pkmax(aA3, (unsigned)__shfl_xor((int)aA3, 32));
    aB0 = pkmax(aB0, (unsigned)__shfl_xor((int)aB0, 32));
    aB1 = pkmax(aB1, (unsigned)__shfl_xor((int)aB1, 32));
    aB2 = pkmax(aB2, (unsigned)__shfl_xor((int)aB2, 32));
    aB3 = pkmax(aB3, (unsigned)__shfl_xor((int)aB3, 32));
    // lanes 0..15 write node A's row, lanes 16..31 write node B's (coalesced pair)
    if (lane < 16) {
        uint4 o;
        if (mA > 0) { o.x = aA0; o.y = aA1; o.z = aA2; o.w = aA3; }
        else        { o.x = o.y = o.z = o.w = 0u; }          // enc(0)==0
        aggrE[(size_t)nA * 16 + lane] = o;
    } else if (lane < 32 && nB < nN) {
        uint4 o;
        if (mB > 0) { o.x = aB0; o.y = aB1; o.z = aB2; o.w = aB3; }
        else        { o.x = o.y = o.z = o.w = 0u; }
        aggrE[(size_t)nB * 16 + (lane - 16)] = o;
    }
}

// ---------------- lean SAGE GEMM: no LDS, no barriers ----------------
// Wave owns 32 rows (2 M-tiles) x BN. A (agg & root, both encoded) read as
// fragments straight from global, decoded in-flight. B from packed Wf (L2-hot).
template<int BN, bool RELU, bool ENCOUT, typename OutT>
__global__ __launch_bounds__(256, 4) void sage_gemm_lean(
        const uint4* __restrict__ AggE,            // [M][16] encoded bf16
        const uint4* __restrict__ RootE,           // [M][16] encoded bf16
        const uint4* __restrict__ Wf,              // fragment-packed weights
        const float* __restrict__ bias,            // [BN] f32
        OutT* __restrict__ C,                      // [M][BN]
        int M) {
    constexpr int NT = BN / 16;
    const int tid = threadIdx.x;
    const int w = tid >> 6;
    const int lane = tid & 63;
    const int quad = lane >> 4;
    const int mrow = lane & 15;
    const int base0 = blockIdx.x * 128 + w * 32;

    const int r0 = min(base0 + mrow, M - 1);
    const int r1 = min(base0 + 16 + mrow, M - 1);

    f32x4 acc[2][NT];
#pragma unroll
    for (int mt = 0; mt < 2; ++mt)
#pragma unroll
        for (int nt = 0; nt < NT; ++nt) acc[mt][nt] = (f32x4){0.f, 0.f, 0.f, 0.f};

#pragma unroll
    for (int kt = 0; kt < 4; ++kt) {
        uint4 ta0 = AggE[(size_t)r0 * 16 + kt * 4 + quad];
        uint4 ta1 = AggE[(size_t)r1 * 16 + kt * 4 + quad];
        uint4 tr0 = RootE[(size_t)r0 * 16 + kt * 4 + quad];
        uint4 tr1 = RootE[(size_t)r1 * 16 + kt * 4 + quad];
        ta0.x = encdec(ta0.x); ta0.y = encdec(ta0.y); ta0.z = encdec(ta0.z); ta0.w = encdec(ta0.w);
        ta1.x = encdec(ta1.x); ta1.y = encdec(ta1.y); ta1.z = encdec(ta1.z); ta1.w = encdec(ta1.w);
        tr0.x = encdec(tr0.x); tr0.y = encdec(tr0.y); tr0.z = encdec(tr0.z); tr0.w = encdec(tr0.w);
        tr1.x = encdec(tr1.x); tr1.y = encdec(tr1.y); tr1.z = encdec(tr1.z); tr1.w = encdec(tr1.w);
        bf16x8 aa0 = __builtin_bit_cast(bf16x8, ta0);
        bf16x8 aa1 = __builtin_bit_cast(bf16x8, ta1);
        bf16x8 ar0 = __builtin_bit_cast(bf16x8, tr0);
        bf16x8 ar1 = __builtin_bit_cast(bf16x8, tr1);
#pragma unroll
        for (int nt = 0; nt < NT; ++nt) {
            bf16x8 b0 = __builtin_bit_cast(bf16x8, Wf[(kt * NT + nt) * 64 + lane]);
            acc[0][nt] = __builtin_amdgcn_mfma_f32_16x16x32_bf16(aa0, b0, acc[0][nt], 0, 0, 0);
            acc[1][nt] = __builtin_amdgcn_mfma_f32_16x16x32_bf16(aa1, b0, acc[1][nt], 0, 0, 0);
            bf16x8 b1 = __builtin_bit_cast(bf16x8, Wf[((4 + kt) * NT + nt) * 64 + lane]);
            acc[0][nt] = __builtin_amdgcn_mfma_f32_16x16x32_bf16(ar0, b1, acc[0][nt], 0, 0, 0);
            acc[1][nt] = __builtin_amdgcn_mfma_f32_16x16x32_bf16(ar1, b1, acc[1][nt], 0, 0, 0);
        }
    }

    // epilogue: D layout col=lane&15, row=quad*4+reg
#pragma unroll
    for (int mt = 0; mt < 2; ++mt) {
        const int rowD = base0 + mt * 16 + quad * 4;
#pragma unroll
        for (int nt = 0; nt < NT; ++nt) {
            int col = nt * 16 + mrow;
            float bv = bias[col];
#pragma unroll
            for (int r = 0; r < 4; ++r) {
                int grow = rowD + r;
                if (grow < M) {
                    float v = acc[mt][nt][r] + bv;
                    if (RELU) v = fmaxf(v, 0.0f);
                    if constexpr (ENCOUT) {
                        unsigned u = f2bf_rne(v);
                        u ^= ((u >> 15) & 1u) * 0x7FFFu;   // encode for next layer
                        C[(size_t)grow * BN + col] = (OutT)u;
                    } else {
                        C[(size_t)grow * BN + col] = (OutT)v;
                    }
                }
            }
        }
    }
}

extern "C" void kernel_launch(void* const* d_in, const int* in_sizes, int n_in,
                              void* d_out, int out_size, void* d_ws, size_t ws_size,
                              hipStream_t stream) {
    const float* x   = (const float*)d_in[0];
    const int*   ei  = (const int*)d_in[1];
    const float* W1l = (const float*)d_in[2];
    const float* b1l = (const float*)d_in[3];
    const float* W1r = (const float*)d_in[4];
    const float* W2l = (const float*)d_in[5];
    const float* b2l = (const float*)d_in[6];
    const float* W2r = (const float*)d_in[7];
    float* out = (float*)d_out;

    const int* src = ei;
    const int* dst = ei + NEDGES;

    // ---- workspace layout ----
    char* ws = (char*)d_ws;
    unsigned short* xe    = (unsigned short*)ws; ws += (size_t)NNODES * 128 * 2;  // 25.6 MB (encoded)
    unsigned short* he    = (unsigned short*)ws; ws += (size_t)NNODES * 128 * 2;  // 25.6 MB (encoded)
    unsigned short* aggrE = (unsigned short*)ws; ws += (size_t)NNODES * 128 * 2;  // 25.6 MB (encoded)
    unsigned int* binArr    = (unsigned int*)ws; ws += (size_t)NBKT * CAP * 4;    // 7.2 MB
    unsigned int* sortedSrc = (unsigned int*)ws; ws += (size_t)NBKT * CAP * 4;    // 7.2 MB
    int* rowBeg     = (int*)ws; ws += (size_t)NNODES * 4;
    int* rowEnd     = (int*)ws; ws += (size_t)NNODES * 4;
    int* bucketFill = (int*)ws; ws += 256 * 4;
    uint4* Wf1 = (uint4*)ws; ws += 4096 * 16;   // 64 KB fragment-packed L1 weights
    uint4* Wf2 = (uint4*)ws; ws += 2048 * 16;   // 32 KB fragment-packed L2 weights

    const int gAgg = (NNODES + 7) / 8;       // 12500
    const int gGemm = (NNODES + 127) / 128;  // 782

    prep1_kernel<<<25, 256, 0, stream>>>(W1l, W1r, W2l, W2r, Wf1, Wf2, bucketFill);
    prep2_kernel<<<GBIN + GCVT, 256, 0, stream>>>(src, dst, binArr, bucketFill,
                                                  (const float4*)x, (uint4*)xe, NEDGES);
    build_csr_kernel<<<NBKT, 512, 0, stream>>>(binArr, bucketFill, sortedSrc, rowBeg, rowEnd);

    // ---- layer 1 ----
    aggregate_pk2<<<gAgg, 256, 0, stream>>>((const uint4*)xe, rowBeg, rowEnd, sortedSrc,
                                            (uint4*)aggrE, NNODES);
    sage_gemm_lean<128, true, true, unsigned short><<<gGemm, 256, 0, stream>>>(
        (const uint4*)aggrE, (const uint4*)xe, Wf1, b1l, he, NNODES);
    // ---- layer 2 ----
    aggregate_pk2<<<gAgg, 256, 0, stream>>>((const uint4*)he, rowBeg, rowEnd, sortedSrc,
                                            (uint4*)aggrE, NNODES);
    sage_gemm_lean<64, false, false, float><<<gGemm, 256, 0, stream>>>(
        (const uint4*)aggrE, (const uint4*)he, Wf2, b2l, out, NNODES);
}